// Round 3
// baseline (35598.248 us; speedup 1.0000x reference)
//
#include <hip/hip_runtime.h>
#include <hip/hip_bf16.h>

// Dimensions (fixed by the problem)
//   B=64 graphs, N=512 points/graph, F0=6, K=8 neighbors, C=256 conv out,
//   H=336 hidden, m1 input 1030, head 256->128->3.
// Dtypes: fp32 in, fp32 out (reference dtypes; the test label's "bf16" is
// cosmetic — R2 proved the out buffer is read as fp32).

#define DEVFN __device__ __forceinline__

DEVFN float lrelu(float v) { return v >= 0.f ? v : 0.01f * v; }

// ---------------------------------------------------------------------------
// squared norms per point
// ---------------------------------------------------------------------------
template<int F>
__global__ __launch_bounds__(256) void norms_kernel(const float* __restrict__ f,
                                                    float* __restrict__ nrm) {
    int p = blockIdx.x * 256 + threadIdx.x;
    if (p >= 64 * 512) return;
    const float* r = f + (size_t)p * F;
    float s = 0.f;
    if constexpr (F % 4 == 0) {
        #pragma unroll 8
        for (int i = 0; i < F; i += 4) {
            float4 v = *(const float4*)(r + i);
            s += v.x * v.x + v.y * v.y + v.z * v.z + v.w * v.w;
        }
    } else {
        #pragma unroll
        for (int i = 0; i < F; ++i) s += r[i] * r[i];
    }
    nrm[p] = s;
}

// ---------------------------------------------------------------------------
// kNN: per block = 32 query points of one graph. Tiled 32x32 distance tiles,
// stable top-8 (ties -> lowest index, matching jax.lax.top_k).
// d = |q|^2 + |c|^2 - 2 q.c  (same formula as reference)
// ---------------------------------------------------------------------------
template<int F>
__global__ __launch_bounds__(256) void knn_kernel(const float* __restrict__ feat,
                                                  const float* __restrict__ nrm,
                                                  int* __restrict__ knn) {
    constexpr int FP = (F == 6) ? 8 : (F + 4);
    __shared__ float Xq[32 * FP];
    __shared__ float Xc[32 * FP];
    __shared__ float qn[32], cn[32];
    __shared__ float dt[32 * 33];
    const int t  = threadIdx.x;
    const int b  = blockIdx.x >> 4;
    const int n0 = (blockIdx.x & 15) << 5;
    const float* fg = feat + (size_t)b * 512 * F;

    for (int i = t; i < 32 * F; i += 256) {
        int r = i / F, c = i - r * F;
        Xq[r * FP + c] = fg[(size_t)(n0 + r) * F + c];
    }
    if (t < 32) qn[t] = nrm[b * 512 + n0 + t];

    float d8[8]; int i8[8];
    #pragma unroll
    for (int k = 0; k < 8; ++k) { d8[k] = 3.4e38f; i8[k] = 0; }

    const int q = t >> 3, cs = t & 7;   // q in 0..31, candidates cs+8j

    for (int ct = 0; ct < 16; ++ct) {
        const int c0 = ct << 5;
        __syncthreads();
        for (int i = t; i < 32 * F; i += 256) {
            int r = i / F, c = i - r * F;
            Xc[r * FP + c] = fg[(size_t)(c0 + r) * F + c];
        }
        if (t < 32) cn[t] = nrm[b * 512 + c0 + t];
        __syncthreads();

        float acc[4] = {0.f, 0.f, 0.f, 0.f};
        if constexpr (F % 4 == 0) {
            const float* xq  = Xq + q * FP;
            const float* xcb = Xc + cs * FP;
            for (int f = 0; f < F; f += 4) {
                float4 qv = *(const float4*)(xq + f);
                #pragma unroll
                for (int j = 0; j < 4; ++j) {
                    float4 cv = *(const float4*)(xcb + j * 8 * FP + f);
                    acc[j] += qv.x * cv.x + qv.y * cv.y + qv.z * cv.z + qv.w * cv.w;
                }
            }
        } else {
            #pragma unroll
            for (int f = 0; f < F; ++f) {
                float qv = Xq[q * FP + f];
                #pragma unroll
                for (int j = 0; j < 4; ++j) acc[j] += qv * Xc[(cs + 8 * j) * FP + f];
            }
        }
        #pragma unroll
        for (int j = 0; j < 4; ++j)
            dt[q * 33 + cs + 8 * j] = qn[q] + cn[cs + 8 * j] - 2.f * acc[j];
        __syncthreads();

        if (t < 32) {
            #pragma unroll 1
            for (int i = 0; i < 32; ++i) {
                float d = dt[t * 33 + i];
                if (d < d8[7]) {             // strict: keeps earlier index on ties
                    d8[7] = d; i8[7] = c0 + i;
                    #pragma unroll
                    for (int s = 7; s >= 1; --s) {
                        if (d8[s] < d8[s - 1]) {   // strict: stable bubble
                            float td = d8[s]; d8[s] = d8[s - 1]; d8[s - 1] = td;
                            int   ti = i8[s]; i8[s] = i8[s - 1]; i8[s - 1] = ti;
                        }
                    }
                }
            }
        }
    }
    if (t < 32) {
        #pragma unroll
        for (int k = 0; k < 8; ++k)
            knn[((size_t)b * 512 + n0 + t) * 8 + k] = i8[k];
    }
}

// ---------------------------------------------------------------------------
// Fused 2-layer MLP.
// MODE 0 (edge conv): 8 points/block -> 64 edge rows E=[xi, xj-xi] (DIN=2F),
//   GEMM1 (DIN->336, lrelu) in 3 chunks of 112 cols staged to LDS,
//   GEMM2 (336->256, lrelu) accumulated in regs, then max over the 8 edges.
// MODE 1 (m1): 64 points/block, rows are the concat [xb|x1|x2|x3|x4] (DIN=1030),
//   same GEMMs, no max, outputs per point.
// ---------------------------------------------------------------------------
template<int DIN, int F, int MODE>
__global__ __launch_bounds__(256)
void mlp_kernel(const float* __restrict__ fA,
                const float* __restrict__ x1f, const float* __restrict__ x2f,
                const float* __restrict__ x3f, const float* __restrict__ x4f,
                const int* __restrict__ knn,
                const float* __restrict__ W1, const float* __restrict__ B1,
                const float* __restrict__ W2, const float* __restrict__ B2,
                float* __restrict__ outf) {
    constexpr int KCN = (DIN + 63) >> 6;
    __shared__ float Et[64 * 65];
    __shared__ float h1c[64 * 113];
    __shared__ int rowi[64];
    __shared__ int rowj[64];
    const int t  = threadIdx.x;
    const int p0 = blockIdx.x * (MODE == 0 ? 8 : 64);

    if (t < 64) {
        if (MODE == 0) {
            int pt = p0 + (t >> 3);
            int b  = pt >> 9;
            rowi[t] = pt;
            rowj[t] = (b << 9) + knn[pt * 8 + (t & 7)];
        } else {
            rowi[t] = p0 + t;
        }
    }

    const int rg = t >> 4, cg = t & 15;           // GEMM1: rows rg*4+i, cols cg+16j
    const int pp = t >> 5, c2 = (t & 31) << 3;    // GEMM2: rows pp*8+j, cols c2..c2+7

    float acc2[8][8];
    #pragma unroll
    for (int a = 0; a < 8; ++a)
        #pragma unroll
        for (int bb = 0; bb < 8; ++bb) acc2[a][bb] = 0.f;

    for (int nc = 0; nc < 3; ++nc) {
        const int nc0 = nc * 112;
        float acc1[4][7];
        #pragma unroll
        for (int a = 0; a < 4; ++a)
            #pragma unroll
            for (int bb = 0; bb < 7; ++bb) acc1[a][bb] = 0.f;

        for (int kc = 0; kc < KCN; ++kc) {
            const int kc0 = kc << 6;
            __syncthreads();
            // stage E tile [64][64] (zero-padded past DIN)
            #pragma unroll
            for (int s = 0; s < 16; ++s) {
                int i = t + s * 256;
                int r = i >> 6, c = i & 63;
                int col = kc0 + c;
                float v = 0.f;
                if (col < DIN) {
                    if (MODE == 0) {
                        if (col < F) {
                            v = fA[(size_t)rowi[r] * F + col];
                        } else {
                            int cc = col - F;
                            v = fA[(size_t)rowj[r] * F + cc] - fA[(size_t)rowi[r] * F + cc];
                        }
                    } else {
                        int pt = rowi[r];
                        if (col < 6) {
                            v = fA[pt * 6 + col];
                        } else {
                            int u = col - 6;
                            const float* fb = (u >> 8) == 0 ? x1f
                                            : (u >> 8) == 1 ? x2f
                                            : (u >> 8) == 2 ? x3f : x4f;
                            v = fb[(size_t)pt * 256 + (u & 255)];
                        }
                    }
                }
                Et[r * 65 + c] = v;
            }
            __syncthreads();

            const float* w1p = W1 + (size_t)kc0 * 336 + nc0 + cg;
            const float* ap  = Et + rg * 4 * 65;
            #pragma unroll 4
            for (int k = 0; k < 64; ++k) {
                float a0 = ap[k], a1 = ap[65 + k], a2 = ap[130 + k], a3 = ap[195 + k];
                #pragma unroll
                for (int j = 0; j < 7; ++j) {
                    float w = w1p[k * 336 + 16 * j];
                    acc1[0][j] += a0 * w;
                    acc1[1][j] += a1 * w;
                    acc1[2][j] += a2 * w;
                    acc1[3][j] += a3 * w;
                }
            }
        }
        __syncthreads();
        // bias + lrelu -> h1 chunk in LDS
        #pragma unroll
        for (int j = 0; j < 7; ++j) {
            float bb = B1[nc0 + cg + 16 * j];
            #pragma unroll
            for (int i = 0; i < 4; ++i)
                h1c[(rg * 4 + i) * 113 + cg + 16 * j] = lrelu(acc1[i][j] + bb);
        }
        __syncthreads();
        // GEMM2 partial over this chunk's 112 k values
        const float* w2p = W2 + (size_t)nc0 * 256 + c2;
        const float* hp  = h1c + pp * 8 * 113;
        #pragma unroll 2
        for (int kk = 0; kk < 112; ++kk) {
            float av[8];
            #pragma unroll
            for (int j = 0; j < 8; ++j) av[j] = hp[j * 113 + kk];
            float4 w0 = *(const float4*)(w2p + kk * 256);
            float4 w1v = *(const float4*)(w2p + kk * 256 + 4);
            #pragma unroll
            for (int j = 0; j < 8; ++j) {
                acc2[j][0] += av[j] * w0.x;  acc2[j][1] += av[j] * w0.y;
                acc2[j][2] += av[j] * w0.z;  acc2[j][3] += av[j] * w0.w;
                acc2[j][4] += av[j] * w1v.x; acc2[j][5] += av[j] * w1v.y;
                acc2[j][6] += av[j] * w1v.z; acc2[j][7] += av[j] * w1v.w;
            }
        }
    }

    // epilogue
    float4 bb0 = *(const float4*)(B2 + c2);
    float4 bb1 = *(const float4*)(B2 + c2 + 4);
    float bia[8] = {bb0.x, bb0.y, bb0.z, bb0.w, bb1.x, bb1.y, bb1.z, bb1.w};
    if (MODE == 0) {
        float mx[8];
        #pragma unroll
        for (int ci = 0; ci < 8; ++ci) {
            float m = -3.4e38f;
            #pragma unroll
            for (int j = 0; j < 8; ++j) {
                float v = lrelu(acc2[j][ci] + bia[ci]);
                m = v > m ? v : m;
            }
            mx[ci] = m;
        }
        int pt = p0 + pp;
        float4 o0 = {mx[0], mx[1], mx[2], mx[3]};
        float4 o1 = {mx[4], mx[5], mx[6], mx[7]};
        *(float4*)(outf + (size_t)pt * 256 + c2) = o0;
        *(float4*)(outf + (size_t)pt * 256 + c2 + 4) = o1;
    } else {
        #pragma unroll
        for (int j = 0; j < 8; ++j) {
            int pt = p0 + pp * 8 + j;
            float4 o0 = {lrelu(acc2[j][0] + bia[0]), lrelu(acc2[j][1] + bia[1]),
                         lrelu(acc2[j][2] + bia[2]), lrelu(acc2[j][3] + bia[3])};
            float4 o1 = {lrelu(acc2[j][4] + bia[4]), lrelu(acc2[j][5] + bia[5]),
                         lrelu(acc2[j][6] + bia[6]), lrelu(acc2[j][7] + bia[7])};
            *(float4*)(outf + (size_t)pt * 256 + c2) = o0;
            *(float4*)(outf + (size_t)pt * 256 + c2 + 4) = o1;
        }
    }
}

// ---------------------------------------------------------------------------
// mean pool over the 512 points of each graph
// ---------------------------------------------------------------------------
__global__ __launch_bounds__(256) void pool_kernel(const float* __restrict__ h,
                                                   float* __restrict__ g) {
    int b = blockIdx.x, t = threadIdx.x;
    const float* hb = h + (size_t)b * 512 * 256;
    float s = 0.f;
    for (int n = 0; n < 512; ++n) s += hb[n * 256 + t];
    g[b * 256 + t] = s * (1.f / 512.f);
}

// ---------------------------------------------------------------------------
// head: lrelu(g @ W1 + b1) @ W2 + b2 -> fp32 out [64,3]
// ---------------------------------------------------------------------------
__global__ __launch_bounds__(128) void head_kernel(const float* __restrict__ g,
                                                   const float* __restrict__ w1,
                                                   const float* __restrict__ b1,
                                                   const float* __restrict__ w2,
                                                   const float* __restrict__ b2,
                                                   float* __restrict__ out) {
    __shared__ float gs[256];
    __shared__ float hid[128];
    int b = blockIdx.x, t = threadIdx.x;
    gs[t] = g[b * 256 + t];
    gs[t + 128] = g[b * 256 + t + 128];
    __syncthreads();
    float s = b1[t];
    for (int c = 0; c < 256; ++c) s += gs[c] * w1[c * 128 + t];
    hid[t] = lrelu(s);
    __syncthreads();
    if (t < 3) {
        float o = b2[t];
        for (int j = 0; j < 128; ++j) o += hid[j] * w2[j * 3 + t];
        out[b * 3 + t] = o;          // fp32 output (reference dtype)
    }
}

// ---------------------------------------------------------------------------
extern "C" void kernel_launch(void* const* d_in, const int* in_sizes, int n_in,
                              void* d_out, int out_size, void* d_ws, size_t ws_size,
                              hipStream_t stream) {
    float* ws = (float*)d_ws;

    // inputs (fp32 per reference dtype; edge_index/batch unused)
    const float* xb = (const float*)d_in[0];
    const float* c_w1[4] = { (const float*)d_in[3],  (const float*)d_in[7],
                             (const float*)d_in[11], (const float*)d_in[15] };
    const float* c_b1[4] = { (const float*)d_in[4],  (const float*)d_in[8],
                             (const float*)d_in[12], (const float*)d_in[16] };
    const float* c_w2[4] = { (const float*)d_in[5],  (const float*)d_in[9],
                             (const float*)d_in[13], (const float*)d_in[17] };
    const float* c_b2[4] = { (const float*)d_in[6],  (const float*)d_in[10],
                             (const float*)d_in[14], (const float*)d_in[18] };
    const float* m1w1 = (const float*)d_in[19];
    const float* m1b1 = (const float*)d_in[20];
    const float* m1w2 = (const float*)d_in[21];
    const float* m1b2 = (const float*)d_in[22];
    const float* m2w1 = (const float*)d_in[23];
    const float* m2b1 = (const float*)d_in[24];
    const float* m2w2 = (const float*)d_in[25];
    const float* m2b2 = (const float*)d_in[26];

    // workspace layout (float units)
    constexpr size_t NRM = 0;                 // 32768
    constexpr size_t KNN = 32768;             // 262144 ints
    constexpr size_t X1o = KNN + 262144;      // 4 x 8388608 feature bufs
    constexpr size_t X2o = X1o + 8388608;
    constexpr size_t X3o = X2o + 8388608;
    constexpr size_t X4o = X3o + 8388608;
    constexpr size_t HMo = X4o + 8388608;     // 8388608 (m1 output)
    constexpr size_t Go  = HMo + 8388608;     // 16384

    float* nrm = ws + NRM;
    int*   knn = (int*)(ws + KNN);
    float* X[4] = { ws + X1o, ws + X2o, ws + X3o, ws + X4o };
    float* hm = ws + HMo;
    float* g  = ws + Go;

    // layer 1 (F=6)
    norms_kernel<6><<<128, 256, 0, stream>>>(xb, nrm);
    knn_kernel<6><<<1024, 256, 0, stream>>>(xb, nrm, knn);
    mlp_kernel<12, 6, 0><<<4096, 256, 0, stream>>>(
        xb, nullptr, nullptr, nullptr, nullptr, knn,
        c_w1[0], c_b1[0], c_w2[0], c_b2[0], X[0]);

    // layers 2..4 (F=256)
    for (int l = 1; l < 4; ++l) {
        norms_kernel<256><<<128, 256, 0, stream>>>(X[l - 1], nrm);
        knn_kernel<256><<<1024, 256, 0, stream>>>(X[l - 1], nrm, knn);
        mlp_kernel<512, 256, 0><<<4096, 256, 0, stream>>>(
            X[l - 1], nullptr, nullptr, nullptr, nullptr, knn,
            c_w1[l], c_b1[l], c_w2[l], c_b2[l], X[l]);
    }

    // m1 over concat [xb|x1|x2|x3|x4]
    mlp_kernel<1030, 6, 1><<<512, 256, 0, stream>>>(
        xb, X[0], X[1], X[2], X[3], nullptr,
        m1w1, m1b1, m1w2, m1b2, hm);

    pool_kernel<<<64, 256, 0, stream>>>(hm, g);
    head_kernel<<<64, 128, 0, stream>>>(g, m2w1, m2b1, m2w2, m2b2,
                                        (float*)d_out);
}

// Round 4
// 2769.988 us; speedup vs baseline: 12.8514x; 12.8514x over previous
//
#include <hip/hip_runtime.h>
#include <hip/hip_bf16.h>

// B=64 graphs, N=512 pts, F0=6, K=8, conv out C=256, hidden H=336,
// m1 in 1030 (pad->1056), head 256->128->3.  fp32 in/out.
// Edge MLPs run as bf16 MFMA (fp32 accum); kNN stays fp32.

#define DEVFN __device__ __forceinline__
DEVFN float lrelu(float v) { return v >= 0.f ? v : 0.01f * v; }

using bf16x8 = __attribute__((ext_vector_type(8))) short;
using f32x4  = __attribute__((ext_vector_type(4))) float;

DEVFN unsigned short f2bf(float v) {
    __hip_bfloat16 h = __float2bfloat16(v);
    return *(unsigned short*)&h;
}

// ---------------------------------------------------------------------------
// weight packing: fp32 [K][N] -> bf16 B-fragment layout [kt][nt][lane][8]
//   frag elem j of lane l = B[kt*32 + (l>>4)*8 + j][nt*16 + (l&15)]
// mode 0: plain, rows >= Ksrc are zero (W2s)
// mode 1: conv W1 split: r<p1 -> src[r]-src[r+p1]; p0<=r<p0+p1 -> src[r-p0+p1]
// mode 2: m1 W1: r<6 -> src[r]; 32<=r -> src[r-26]; else 0
// ---------------------------------------------------------------------------
struct PDesc { const float* src; unsigned short* dst; int Kt, NT, N, mode, p0, p1, Ksrc; };
struct PTable { PDesc d[10]; };

__global__ __launch_bounds__(256) void pack_kernel(PTable tb) {
    PDesc d = tb.d[blockIdx.y];
    int i = blockIdx.x * 256 + threadIdx.x;
    int tot = d.Kt * d.NT * 512;
    if (i >= tot) return;
    int j = i & 7, lane = (i >> 3) & 63;
    int tile = i >> 9;
    int nt = tile % d.NT, kt = tile / d.NT;
    int k = kt * 32 + ((lane >> 4) << 3) + j;
    int n = nt * 16 + (lane & 15);
    float v = 0.f;
    if (d.mode == 0) {
        if (k < d.Ksrc) v = d.src[(size_t)k * d.N + n];
    } else if (d.mode == 1) {
        if (k < d.p1) v = d.src[(size_t)k * d.N + n] - d.src[(size_t)(k + d.p1) * d.N + n];
        else if (k >= d.p0 && k < d.p0 + d.p1) v = d.src[(size_t)(k - d.p0 + d.p1) * d.N + n];
    } else {
        if (k < 6) v = d.src[(size_t)k * d.N + n];
        else if (k >= 32 && k < 1056) v = d.src[(size_t)(k - 26) * d.N + n];
    }
    d.dst[i] = f2bf(v);
}

// ---------------------------------------------------------------------------
// xb prep: bf16 row [16] (6 vals + 10 zeros) and Xcat cols 0..31 (6 vals + 26 z)
// ---------------------------------------------------------------------------
__global__ __launch_bounds__(256) void xbprep_kernel(const float* __restrict__ xb,
                                                     unsigned short* __restrict__ xbbf,
                                                     unsigned short* __restrict__ xcat) {
    int p = blockIdx.x * 256 + threadIdx.x;
    if (p >= 32768) return;
    unsigned short r[16];
    #pragma unroll
    for (int c = 0; c < 6; ++c) r[c] = f2bf(xb[p * 6 + c]);
    #pragma unroll
    for (int c = 6; c < 16; ++c) r[c] = 0;
    #pragma unroll
    for (int c = 0; c < 16; ++c) xbbf[p * 16 + c] = r[c];
    unsigned short* xc = xcat + (size_t)p * 1056;
    #pragma unroll
    for (int c = 0; c < 16; ++c) xc[c] = r[c];
    #pragma unroll
    for (int c = 16; c < 32; ++c) xc[c] = 0;
}

// ---------------------------------------------------------------------------
// squared norms per point (fp32)
// ---------------------------------------------------------------------------
template<int F>
__global__ __launch_bounds__(256) void norms_kernel(const float* __restrict__ f,
                                                    float* __restrict__ nrm) {
    int p = blockIdx.x * 256 + threadIdx.x;
    if (p >= 64 * 512) return;
    const float* r = f + (size_t)p * F;
    float s = 0.f;
    if constexpr (F % 4 == 0) {
        #pragma unroll 8
        for (int i = 0; i < F; i += 4) {
            float4 v = *(const float4*)(r + i);
            s += v.x * v.x + v.y * v.y + v.z * v.z + v.w * v.w;
        }
    } else {
        #pragma unroll
        for (int i = 0; i < F; ++i) s += r[i] * r[i];
    }
    nrm[p] = s;
}

// ---------------------------------------------------------------------------
// kNN (fp32): 32 queries/block, stable top-8 (ties -> lowest index)
// ---------------------------------------------------------------------------
template<int F>
__global__ __launch_bounds__(256) void knn_kernel(const float* __restrict__ feat,
                                                  const float* __restrict__ nrm,
                                                  int* __restrict__ knn) {
    constexpr int FP = (F == 6) ? 8 : (F + 4);
    __shared__ float Xq[32 * FP];
    __shared__ float Xc[32 * FP];
    __shared__ float qn[32], cn[32];
    __shared__ float dt[32 * 33];
    const int t  = threadIdx.x;
    const int b  = blockIdx.x >> 4;
    const int n0 = (blockIdx.x & 15) << 5;
    const float* fg = feat + (size_t)b * 512 * F;

    for (int i = t; i < 32 * F; i += 256) {
        int r = i / F, c = i - r * F;
        Xq[r * FP + c] = fg[(size_t)(n0 + r) * F + c];
    }
    if (t < 32) qn[t] = nrm[b * 512 + n0 + t];

    float d8[8]; int i8[8];
    #pragma unroll
    for (int k = 0; k < 8; ++k) { d8[k] = 3.4e38f; i8[k] = 0; }

    const int q = t >> 3, cs = t & 7;

    for (int ct = 0; ct < 16; ++ct) {
        const int c0 = ct << 5;
        __syncthreads();
        for (int i = t; i < 32 * F; i += 256) {
            int r = i / F, c = i - r * F;
            Xc[r * FP + c] = fg[(size_t)(c0 + r) * F + c];
        }
        if (t < 32) cn[t] = nrm[b * 512 + c0 + t];
        __syncthreads();

        float acc[4] = {0.f, 0.f, 0.f, 0.f};
        if constexpr (F % 4 == 0) {
            const float* xq  = Xq + q * FP;
            const float* xcb = Xc + cs * FP;
            for (int f = 0; f < F; f += 4) {
                float4 qv = *(const float4*)(xq + f);
                #pragma unroll
                for (int j = 0; j < 4; ++j) {
                    float4 cv = *(const float4*)(xcb + j * 8 * FP + f);
                    acc[j] += qv.x * cv.x + qv.y * cv.y + qv.z * cv.z + qv.w * cv.w;
                }
            }
        } else {
            #pragma unroll
            for (int f = 0; f < F; ++f) {
                float qv = Xq[q * FP + f];
                #pragma unroll
                for (int j = 0; j < 4; ++j) acc[j] += qv * Xc[(cs + 8 * j) * FP + f];
            }
        }
        #pragma unroll
        for (int j = 0; j < 4; ++j)
            dt[q * 33 + cs + 8 * j] = qn[q] + cn[cs + 8 * j] - 2.f * acc[j];
        __syncthreads();

        if (t < 32) {
            #pragma unroll 1
            for (int i = 0; i < 32; ++i) {
                float d = dt[t * 33 + i];
                if (d < d8[7]) {
                    d8[7] = d; i8[7] = c0 + i;
                    #pragma unroll
                    for (int s = 7; s >= 1; --s) {
                        if (d8[s] < d8[s - 1]) {
                            float td = d8[s]; d8[s] = d8[s - 1]; d8[s - 1] = td;
                            int   ti = i8[s]; i8[s] = i8[s - 1]; i8[s - 1] = ti;
                        }
                    }
                }
            }
        }
    }
    if (t < 32) {
        #pragma unroll
        for (int k = 0; k < 8; ++k)
            knn[((size_t)b * 512 + n0 + t) * 8 + k] = i8[k];
    }
}

// ---------------------------------------------------------------------------
// MFMA fused 2-layer MLP.
// MODE 0: conv F=256 (A = [xi | xj], K=512, 2 chunks of 256)
// MODE 1: conv layer1 F=6  (A = [xi6,0..,xj6,0..], K=32, 1 chunk)
// MODE 2: m1 (A = Xcat row, K=1056, 3 chunks of 352), no max, out fp32 only
// GEMM1 -> 336 (21 ntiles), lrelu, bf16 h1 in LDS (K-pad 352), GEMM2 -> 256.
// ---------------------------------------------------------------------------
template<int MODE>
__global__ __launch_bounds__(256, 3)
void mfma_mlp(const unsigned short* __restrict__ featbf, int fstride,
              const int* __restrict__ knn,
              const unsigned short* __restrict__ W1p, const float* __restrict__ B1,
              const unsigned short* __restrict__ W2p, const float* __restrict__ B2,
              float* __restrict__ outf,
              unsigned short* __restrict__ xcat, int sliceoff) {
    constexpr int NCHUNK  = (MODE == 0) ? 2 : (MODE == 1) ? 1 : 3;
    constexpr int KTPC    = (MODE == 0) ? 8 : (MODE == 1) ? 1 : 11;
    constexpr int ASTRIDE = (MODE == 0) ? 264 : (MODE == 1) ? 40 : 360;

    __shared__ unsigned short smem[64 * 360];   // A-chunk (<=45KB) then h1 (45KB)
    __shared__ int rowi[64];
    __shared__ int rowj[64];

    const int t = threadIdx.x;
    const int l = t & 63, w = t >> 6;
    const int q = l >> 4, m16 = l & 15;

    if (MODE != 2 && t < 64) {
        int pt = blockIdx.x * 8 + (t >> 3);
        rowi[t] = pt;
        rowj[t] = (pt & ~511) + knn[pt * 8 + (t & 7)];
    }

    f32x4 acc1[21];
    #pragma unroll
    for (int i = 0; i < 21; ++i) acc1[i] = (f32x4){0.f, 0.f, 0.f, 0.f};

    for (int kc = 0; kc < NCHUNK; ++kc) {
        __syncthreads();
        // ---- stage A chunk (bf16, bank-padded) ----
        if constexpr (MODE == 0) {
            const int r = t >> 2;
            const unsigned short* srow =
                featbf + (size_t)(kc == 0 ? rowi[r] : rowj[r]) * fstride;
            #pragma unroll
            for (int s = 0; s < 8; ++s) {
                int c16 = (t & 3) + (s << 2);
                *(uint4*)&smem[r * 264 + c16 * 8] = *(const uint4*)(srow + c16 * 8);
            }
        } else if constexpr (MODE == 1) {
            const int r = t >> 2, c16 = t & 3;
            const unsigned short* s2 =
                featbf + (size_t)(c16 < 2 ? rowi[r] : rowj[r]) * 16 + (c16 & 1) * 8;
            *(uint4*)&smem[r * 40 + c16 * 8] = *(const uint4*)s2;
        } else {
            const int r = t >> 2;
            const unsigned short* srow =
                featbf + (size_t)(blockIdx.x * 64 + r) * 1056 + kc * 352;
            #pragma unroll
            for (int s = 0; s < 11; ++s) {
                int c16 = (t & 3) + (s << 2);
                *(uint4*)&smem[r * 360 + c16 * 8] = *(const uint4*)(srow + c16 * 8);
            }
        }
        __syncthreads();

        // ---- GEMM1 partial over this chunk ----
        const unsigned short* arow = &smem[(w * 16 + m16) * ASTRIDE + q * 8];
        #pragma unroll 1
        for (int kt = 0; kt < KTPC; ++kt) {
            bf16x8 af = *(const bf16x8*)(arow + kt * 32);
            const unsigned short* bp =
                W1p + ((size_t)(kc * KTPC + kt) * 21 * 64 + l) * 8;
            #pragma unroll
            for (int nt = 0; nt < 21; ++nt) {
                bf16x8 bf = *(const bf16x8*)(bp + nt * 512);
                acc1[nt] = __builtin_amdgcn_mfma_f32_16x16x32_bf16(af, bf, acc1[nt], 0, 0, 0);
            }
        }
    }
    __syncthreads();

    // ---- h1 = lrelu(acc1 + b1) -> bf16 LDS [64][360], pad cols 336..351 = 0 ----
    #pragma unroll
    for (int nt = 0; nt < 21; ++nt) {
        float b = B1[nt * 16 + m16];
        #pragma unroll
        for (int r = 0; r < 4; ++r) {
            float v = lrelu(acc1[nt][r] + b);
            smem[(w * 16 + q * 4 + r) * 360 + nt * 16 + m16] = f2bf(v);
        }
    }
    if (t < 64) {
        #pragma unroll
        for (int c = 336; c < 352; ++c) smem[t * 360 + c] = 0;
    }
    __syncthreads();

    // ---- GEMM2: h1[64][352] x W2[352][256] ----
    f32x4 acc2[16];
    #pragma unroll
    for (int i = 0; i < 16; ++i) acc2[i] = (f32x4){0.f, 0.f, 0.f, 0.f};
    const unsigned short* hrow = &smem[(w * 16 + m16) * 360 + q * 8];
    #pragma unroll 1
    for (int kt = 0; kt < 11; ++kt) {
        bf16x8 af = *(const bf16x8*)(hrow + kt * 32);
        const unsigned short* bp = W2p + ((size_t)kt * 16 * 64 + l) * 8;
        #pragma unroll
        for (int nt = 0; nt < 16; ++nt) {
            bf16x8 bf = *(const bf16x8*)(bp + nt * 512);
            acc2[nt] = __builtin_amdgcn_mfma_f32_16x16x32_bf16(af, bf, acc2[nt], 0, 0, 0);
        }
    }

    // ---- epilogue ----
    if constexpr (MODE != 2) {
        // max over 8 edges: reg-max (4 rows) then quad-pair via shfl_xor 16
        #pragma unroll
        for (int nt = 0; nt < 16; ++nt) {
            float b = B2[nt * 16 + m16];
            float mv = -3.4e38f;
            #pragma unroll
            for (int r = 0; r < 4; ++r) mv = fmaxf(mv, lrelu(acc2[nt][r] + b));
            mv = fmaxf(mv, __shfl_xor(mv, 16, 64));
            if ((q & 1) == 0) {
                int p = blockIdx.x * 8 + w * 2 + (q >> 1);
                int col = nt * 16 + m16;
                outf[(size_t)p * 256 + col] = mv;
                xcat[(size_t)p * 1056 + sliceoff + col] = f2bf(mv);
            }
        }
    } else {
        #pragma unroll
        for (int nt = 0; nt < 16; ++nt) {
            float b = B2[nt * 16 + m16];
            int col = nt * 16 + m16;
            #pragma unroll
            for (int r = 0; r < 4; ++r) {
                int p = blockIdx.x * 64 + w * 16 + q * 4 + r;
                outf[(size_t)p * 256 + col] = lrelu(acc2[nt][r] + b);
            }
        }
    }
}

// ---------------------------------------------------------------------------
// mean pool + head (fp32, tiny)
// ---------------------------------------------------------------------------
__global__ __launch_bounds__(256) void pool_kernel(const float* __restrict__ h,
                                                   float* __restrict__ g) {
    int b = blockIdx.x, t = threadIdx.x;
    const float* hb = h + (size_t)b * 512 * 256;
    float s = 0.f;
    for (int n = 0; n < 512; ++n) s += hb[n * 256 + t];
    g[b * 256 + t] = s * (1.f / 512.f);
}

__global__ __launch_bounds__(128) void head_kernel(const float* __restrict__ g,
                                                   const float* __restrict__ w1,
                                                   const float* __restrict__ b1,
                                                   const float* __restrict__ w2,
                                                   const float* __restrict__ b2,
                                                   float* __restrict__ out) {
    __shared__ float gs[256];
    __shared__ float hid[128];
    int b = blockIdx.x, t = threadIdx.x;
    gs[t] = g[b * 256 + t];
    gs[t + 128] = g[b * 256 + t + 128];
    __syncthreads();
    float s = b1[t];
    for (int c = 0; c < 256; ++c) s += gs[c] * w1[c * 128 + t];
    hid[t] = lrelu(s);
    __syncthreads();
    if (t < 3) {
        float o = b2[t];
        for (int j = 0; j < 128; ++j) o += hid[j] * w2[j * 3 + t];
        out[b * 3 + t] = o;
    }
}

// ---------------------------------------------------------------------------
extern "C" void kernel_launch(void* const* d_in, const int* in_sizes, int n_in,
                              void* d_out, int out_size, void* d_ws, size_t ws_size,
                              hipStream_t stream) {
    const float* xb = (const float*)d_in[0];
    const float* c_w1[4] = { (const float*)d_in[3],  (const float*)d_in[7],
                             (const float*)d_in[11], (const float*)d_in[15] };
    const float* c_b1[4] = { (const float*)d_in[4],  (const float*)d_in[8],
                             (const float*)d_in[12], (const float*)d_in[16] };
    const float* c_w2[4] = { (const float*)d_in[5],  (const float*)d_in[9],
                             (const float*)d_in[13], (const float*)d_in[17] };
    const float* c_b2[4] = { (const float*)d_in[6],  (const float*)d_in[10],
                             (const float*)d_in[14], (const float*)d_in[18] };
    const float* m1w1 = (const float*)d_in[19];
    const float* m1b1 = (const float*)d_in[20];
    const float* m1w2 = (const float*)d_in[21];
    const float* m1b2 = (const float*)d_in[22];
    const float* m2w1 = (const float*)d_in[23];
    const float* m2b1 = (const float*)d_in[24];
    const float* m2w2 = (const float*)d_in[25];
    const float* m2b2 = (const float*)d_in[26];

    // -------- workspace layout (bytes, 256-aligned) --------
    char* base = (char*)d_ws;
    size_t off = 0;
    auto alloc = [&](size_t bytes) { char* p = base + off; off = (off + bytes + 255) & ~(size_t)255; return p; };
    int*            knn   = (int*)           alloc(32768 * 8 * 4);
    float*          nrm   = (float*)         alloc(32768 * 4);
    float*          Xf0   = (float*)         alloc((size_t)32768 * 256 * 4);
    float*          Xf1   = (float*)         alloc((size_t)32768 * 256 * 4);
    float*          hm    = (float*)         alloc((size_t)32768 * 256 * 4);
    float*          g     = (float*)         alloc(64 * 256 * 4);
    unsigned short* xcat  = (unsigned short*)alloc((size_t)32768 * 1056 * 2);
    unsigned short* xbbf  = (unsigned short*)alloc((size_t)32768 * 16 * 2);
    unsigned short* w1p1  = (unsigned short*)alloc((size_t)1  * 21 * 512 * 2);
    unsigned short* w1p2  = (unsigned short*)alloc((size_t)16 * 21 * 512 * 2);
    unsigned short* w1p3  = (unsigned short*)alloc((size_t)16 * 21 * 512 * 2);
    unsigned short* w1p4  = (unsigned short*)alloc((size_t)16 * 21 * 512 * 2);
    unsigned short* w2p1  = (unsigned short*)alloc((size_t)11 * 16 * 512 * 2);
    unsigned short* w2p2  = (unsigned short*)alloc((size_t)11 * 16 * 512 * 2);
    unsigned short* w2p3  = (unsigned short*)alloc((size_t)11 * 16 * 512 * 2);
    unsigned short* w2p4  = (unsigned short*)alloc((size_t)11 * 16 * 512 * 2);
    unsigned short* m1p1  = (unsigned short*)alloc((size_t)33 * 21 * 512 * 2);
    unsigned short* m1p2  = (unsigned short*)alloc((size_t)11 * 16 * 512 * 2);

    // -------- pack weights (bf16 fragment layout) --------
    PTable tb;
    tb.d[0] = { c_w1[0], w1p1, 1,  21, 336, 1, 16,  6,   0    };
    tb.d[1] = { c_w1[1], w1p2, 16, 21, 336, 1, 256, 256, 0    };
    tb.d[2] = { c_w1[2], w1p3, 16, 21, 336, 1, 256, 256, 0    };
    tb.d[3] = { c_w1[3], w1p4, 16, 21, 336, 1, 256, 256, 0    };
    tb.d[4] = { c_w2[0], w2p1, 11, 16, 256, 0, 0,   0,   336  };
    tb.d[5] = { c_w2[1], w2p2, 11, 16, 256, 0, 0,   0,   336  };
    tb.d[6] = { c_w2[2], w2p3, 11, 16, 256, 0, 0,   0,   336  };
    tb.d[7] = { c_w2[3], w2p4, 11, 16, 256, 0, 0,   0,   336  };
    tb.d[8] = { m1w1,    m1p1, 33, 21, 336, 2, 0,   0,   0    };
    tb.d[9] = { m1w2,    m1p2, 11, 16, 256, 0, 0,   0,   336  };
    pack_kernel<<<dim3(1386, 10), dim3(256), 0, stream>>>(tb);
    xbprep_kernel<<<128, 256, 0, stream>>>(xb, xbbf, xcat);

    // -------- layer 1 (F=6) --------
    norms_kernel<6><<<128, 256, 0, stream>>>(xb, nrm);
    knn_kernel<6><<<1024, 256, 0, stream>>>(xb, nrm, knn);
    mfma_mlp<1><<<4096, 256, 0, stream>>>(xbbf, 16, knn,
                                          w1p1, c_b1[0], w2p1, c_b2[0],
                                          Xf0, xcat, 32);

    // -------- layers 2..4 (F=256) --------
    unsigned short* w1ps[3] = { w1p2, w1p3, w1p4 };
    unsigned short* w2ps[3] = { w2p2, w2p3, w2p4 };
    float* Xsrc = Xf0;
    float* Xdst = Xf1;
    for (int l = 1; l < 4; ++l) {
        norms_kernel<256><<<128, 256, 0, stream>>>(Xsrc, nrm);
        knn_kernel<256><<<1024, 256, 0, stream>>>(Xsrc, nrm, knn);
        int srcslice = 32 + (l - 1) * 256;
        int dstslice = 32 + l * 256;
        mfma_mlp<0><<<4096, 256, 0, stream>>>(xcat + srcslice, 1056, knn,
                                              w1ps[l - 1], c_b1[l], w2ps[l - 1], c_b2[l],
                                              Xdst, xcat, dstslice);
        float* tmp = Xsrc; Xsrc = Xdst; Xdst = tmp;
    }

    // -------- m1 over Xcat --------
    mfma_mlp<2><<<512, 256, 0, stream>>>(xcat, 1056, nullptr,
                                         m1p1, m1b1, m1p2, m1b2,
                                         hm, nullptr, 0);

    pool_kernel<<<64, 256, 0, stream>>>(hm, g);
    head_kernel<<<64, 128, 0, stream>>>(g, m2w1, m2b1, m2w2, m2b2, (float*)d_out);
}

// Round 5
// 1770.402 us; speedup vs baseline: 20.1074x; 1.5646x over previous
//
#include <hip/hip_runtime.h>
#include <hip/hip_bf16.h>

// B=64 graphs, N=512 pts, F0=6, K=8, conv out C=256, hidden H=336,
// m1 in 1030 (pad->1056), head 256->128->3.  fp32 in/out.
// Edge MLPs: bf16 MFMA (fp32 accum). kNN layers 2-4: bf16x3 MFMA Gram
// (hi+lo split, fp32-equivalent ordering). Layer-1 kNN (F=6): fp32 VALU.

#define DEVFN __device__ __forceinline__
DEVFN float lrelu(float v) { return v >= 0.f ? v : 0.01f * v; }

using bf16x8 = __attribute__((ext_vector_type(8))) short;
using f32x4  = __attribute__((ext_vector_type(4))) float;

DEVFN unsigned short f2bf(float v) {
    __hip_bfloat16 h = __float2bfloat16(v);
    return *(unsigned short*)&h;
}
DEVFN float bf2f(unsigned short u) {
    return __uint_as_float((unsigned)u << 16);
}

// ---------------------------------------------------------------------------
// weight packing: fp32 [K][N] -> bf16 B-fragment layout [kt][nt][lane][8]
//   frag elem j of lane l = B[kt*32 + (l>>4)*8 + j][nt*16 + (l&15)]
// mode 0: plain, rows >= Ksrc are zero (W2s)
// mode 1: conv W1 split: r<p1 -> src[r]-src[r+p1]; p0<=r<p0+p1 -> src[r-p0+p1]
// mode 2: m1 W1: r<6 -> src[r]; 32<=r -> src[r-26]; else 0
// ---------------------------------------------------------------------------
struct PDesc { const float* src; unsigned short* dst; int Kt, NT, N, mode, p0, p1, Ksrc; };
struct PTable { PDesc d[10]; };

__global__ __launch_bounds__(256) void pack_kernel(PTable tb) {
    PDesc d = tb.d[blockIdx.y];
    int i = blockIdx.x * 256 + threadIdx.x;
    int tot = d.Kt * d.NT * 512;
    if (i >= tot) return;
    int j = i & 7, lane = (i >> 3) & 63;
    int tile = i >> 9;
    int nt = tile % d.NT, kt = tile / d.NT;
    int k = kt * 32 + ((lane >> 4) << 3) + j;
    int n = nt * 16 + (lane & 15);
    float v = 0.f;
    if (d.mode == 0) {
        if (k < d.Ksrc) v = d.src[(size_t)k * d.N + n];
    } else if (d.mode == 1) {
        if (k < d.p1) v = d.src[(size_t)k * d.N + n] - d.src[(size_t)(k + d.p1) * d.N + n];
        else if (k >= d.p0 && k < d.p0 + d.p1) v = d.src[(size_t)(k - d.p0 + d.p1) * d.N + n];
    } else {
        if (k < 6) v = d.src[(size_t)k * d.N + n];
        else if (k >= 32 && k < 1056) v = d.src[(size_t)(k - 26) * d.N + n];
    }
    d.dst[i] = f2bf(v);
}

// ---------------------------------------------------------------------------
// xb prep: bf16 row [16] (6 vals + 10 zeros) and Xcat cols 0..31
// ---------------------------------------------------------------------------
__global__ __launch_bounds__(256) void xbprep_kernel(const float* __restrict__ xb,
                                                     unsigned short* __restrict__ xbbf,
                                                     unsigned short* __restrict__ xcat) {
    int p = blockIdx.x * 256 + threadIdx.x;
    if (p >= 32768) return;
    unsigned short r[16];
    #pragma unroll
    for (int c = 0; c < 6; ++c) r[c] = f2bf(xb[p * 6 + c]);
    #pragma unroll
    for (int c = 6; c < 16; ++c) r[c] = 0;
    #pragma unroll
    for (int c = 0; c < 16; ++c) xbbf[p * 16 + c] = r[c];
    unsigned short* xc = xcat + (size_t)p * 1056;
    #pragma unroll
    for (int c = 0; c < 16; ++c) xc[c] = r[c];
    #pragma unroll
    for (int c = 16; c < 32; ++c) xc[c] = 0;
}

// ---------------------------------------------------------------------------
// squared norms (fp32) — layer 1 only
// ---------------------------------------------------------------------------
template<int F>
__global__ __launch_bounds__(256) void norms_kernel(const float* __restrict__ f,
                                                    float* __restrict__ nrm) {
    int p = blockIdx.x * 256 + threadIdx.x;
    if (p >= 64 * 512) return;
    const float* r = f + (size_t)p * F;
    float s = 0.f;
    #pragma unroll
    for (int i = 0; i < F; ++i) s += r[i] * r[i];
    nrm[p] = s;
}

// ---------------------------------------------------------------------------
// kNN fp32 (layer 1, F=6): 32 queries/block, stable top-8
// ---------------------------------------------------------------------------
template<int F>
__global__ __launch_bounds__(256) void knn_kernel(const float* __restrict__ feat,
                                                  const float* __restrict__ nrm,
                                                  int* __restrict__ knn) {
    constexpr int FP = (F == 6) ? 8 : (F + 4);
    __shared__ float Xq[32 * FP];
    __shared__ float Xc[32 * FP];
    __shared__ float qn[32], cn[32];
    __shared__ float dt[32 * 33];
    const int t  = threadIdx.x;
    const int b  = blockIdx.x >> 4;
    const int n0 = (blockIdx.x & 15) << 5;
    const float* fg = feat + (size_t)b * 512 * F;

    for (int i = t; i < 32 * F; i += 256) {
        int r = i / F, c = i - r * F;
        Xq[r * FP + c] = fg[(size_t)(n0 + r) * F + c];
    }
    if (t < 32) qn[t] = nrm[b * 512 + n0 + t];

    float d8[8]; int i8[8];
    #pragma unroll
    for (int k = 0; k < 8; ++k) { d8[k] = 3.4e38f; i8[k] = 0; }

    const int q = t >> 3, cs = t & 7;

    for (int ct = 0; ct < 16; ++ct) {
        const int c0 = ct << 5;
        __syncthreads();
        for (int i = t; i < 32 * F; i += 256) {
            int r = i / F, c = i - r * F;
            Xc[r * FP + c] = fg[(size_t)(c0 + r) * F + c];
        }
        if (t < 32) cn[t] = nrm[b * 512 + c0 + t];
        __syncthreads();

        float acc[4] = {0.f, 0.f, 0.f, 0.f};
        #pragma unroll
        for (int f = 0; f < F; ++f) {
            float qv = Xq[q * FP + f];
            #pragma unroll
            for (int j = 0; j < 4; ++j) acc[j] += qv * Xc[(cs + 8 * j) * FP + f];
        }
        #pragma unroll
        for (int j = 0; j < 4; ++j)
            dt[q * 33 + cs + 8 * j] = qn[q] + cn[cs + 8 * j] - 2.f * acc[j];
        __syncthreads();

        if (t < 32) {
            #pragma unroll 1
            for (int i = 0; i < 32; ++i) {
                float d = dt[t * 33 + i];
                if (d < d8[7]) {
                    d8[7] = d; i8[7] = c0 + i;
                    #pragma unroll
                    for (int s = 7; s >= 1; --s) {
                        if (d8[s] < d8[s - 1]) {
                            float td = d8[s]; d8[s] = d8[s - 1]; d8[s - 1] = td;
                            int   ti = i8[s]; i8[s] = i8[s - 1]; i8[s - 1] = ti;
                        }
                    }
                }
            }
        }
    }
    if (t < 32) {
        #pragma unroll
        for (int k = 0; k < 8; ++k)
            knn[((size_t)b * 512 + n0 + t) * 8 + k] = i8[k];
    }
}

// ---------------------------------------------------------------------------
// kNN via MFMA Gram (bf16x3): layers 2-4 (F=256).
// Block = 64 queries of one graph; loop over 8 candidate strips of 64;
// K in 4 chunks of 64. Gram = qh*ch + qh*cl + ql*ch (fp32 acc, ~2^-17 rel).
// Top-8 per (query, col-quarter) thread, stable; 4-way sorted merge.
// ---------------------------------------------------------------------------
__global__ __launch_bounds__(256, 2)
void knn_mfma(const unsigned short* __restrict__ xhi,  // stride 1056 (xcat slice)
              const unsigned short* __restrict__ xlo,  // stride 256
              const float* __restrict__ nrm,
              int* __restrict__ knn) {
    __shared__ unsigned short Qh[64 * 72], Ql[64 * 72], Ch[64 * 72], Cl[64 * 72];
    __shared__ float dt[64 * 66];           // aliased as merge buffers at end
    __shared__ float qn[64], cn[64];
    float* mD = dt;                         // [64][4][8]
    int*   mI = (int*)(dt + 2048);          // [64][4][8]

    const int t  = threadIdx.x;
    const int l  = t & 63, w = t >> 6;
    const int m16 = l & 15, q4 = l >> 4;
    const int b  = blockIdx.x >> 3;
    const int qs = (blockIdx.x & 7) << 6;

    if (t < 64) qn[t] = nrm[b * 512 + qs + t];

    float d8[8]; int i8[8];
    #pragma unroll
    for (int k = 0; k < 8; ++k) { d8[k] = 3.4e38f; i8[k] = 0x7fffffff; }

    const int sr = t >> 2;                  // staging row 0..63
    const int sc = (t & 3) << 4;            // staging col base (shorts)
    const int tq = t & 63, sub = t >> 6;    // scan mapping

    for (int cs = 0; cs < 8; ++cs) {
        const int c0 = cs << 6;
        if (t < 64) cn[t] = nrm[b * 512 + c0 + t];

        f32x4 acc[4];
        #pragma unroll
        for (int i = 0; i < 4; ++i) acc[i] = (f32x4){0.f, 0.f, 0.f, 0.f};

        for (int kc = 0; kc < 4; ++kc) {
            const int k0 = kc << 6;
            __syncthreads();
            {
                const unsigned short* qh = xhi + (size_t)(b * 512 + qs + sr) * 1056 + k0 + sc;
                const unsigned short* ql = xlo + (size_t)(b * 512 + qs + sr) * 256  + k0 + sc;
                const unsigned short* ch = xhi + (size_t)(b * 512 + c0 + sr) * 1056 + k0 + sc;
                const unsigned short* cl = xlo + (size_t)(b * 512 + c0 + sr) * 256  + k0 + sc;
                *(uint4*)&Qh[sr * 72 + sc]     = *(const uint4*)(qh);
                *(uint4*)&Qh[sr * 72 + sc + 8] = *(const uint4*)(qh + 8);
                *(uint4*)&Ql[sr * 72 + sc]     = *(const uint4*)(ql);
                *(uint4*)&Ql[sr * 72 + sc + 8] = *(const uint4*)(ql + 8);
                *(uint4*)&Ch[sr * 72 + sc]     = *(const uint4*)(ch);
                *(uint4*)&Ch[sr * 72 + sc + 8] = *(const uint4*)(ch + 8);
                *(uint4*)&Cl[sr * 72 + sc]     = *(const uint4*)(cl);
                *(uint4*)&Cl[sr * 72 + sc + 8] = *(const uint4*)(cl + 8);
            }
            __syncthreads();

            #pragma unroll
            for (int kt = 0; kt < 2; ++kt) {
                const int ko = kt * 32 + q4 * 8;
                bf16x8 ah = *(const bf16x8*)&Qh[(w * 16 + m16) * 72 + ko];
                bf16x8 al = *(const bf16x8*)&Ql[(w * 16 + m16) * 72 + ko];
                #pragma unroll
                for (int nt = 0; nt < 4; ++nt) {
                    bf16x8 bh = *(const bf16x8*)&Ch[(nt * 16 + m16) * 72 + ko];
                    bf16x8 bl = *(const bf16x8*)&Cl[(nt * 16 + m16) * 72 + ko];
                    acc[nt] = __builtin_amdgcn_mfma_f32_16x16x32_bf16(ah, bh, acc[nt], 0, 0, 0);
                    acc[nt] = __builtin_amdgcn_mfma_f32_16x16x32_bf16(ah, bl, acc[nt], 0, 0, 0);
                    acc[nt] = __builtin_amdgcn_mfma_f32_16x16x32_bf16(al, bh, acc[nt], 0, 0, 0);
                }
            }
        }

        // d = qn + cn - 2*Gram  (C layout: row = q4*4+reg, col = m16)
        #pragma unroll
        for (int nt = 0; nt < 4; ++nt) {
            float cv = cn[nt * 16 + m16];
            #pragma unroll
            for (int rr = 0; rr < 4; ++rr) {
                int qr = w * 16 + q4 * 4 + rr;
                dt[qr * 66 + nt * 16 + m16] = qn[qr] + cv - 2.f * acc[nt][rr];
            }
        }
        __syncthreads();

        // stable top-8 update over this thread's 16-col slice
        {
            const float* drow = &dt[tq * 66 + sub * 16];
            #pragma unroll 1
            for (int j = 0; j < 16; ++j) {
                float d = drow[j];
                if (d < d8[7]) {
                    d8[7] = d; i8[7] = c0 + sub * 16 + j;
                    #pragma unroll
                    for (int s = 7; s >= 1; --s) {
                        if (d8[s] < d8[s - 1]) {
                            float td = d8[s]; d8[s] = d8[s - 1]; d8[s - 1] = td;
                            int   ti = i8[s]; i8[s] = i8[s - 1]; i8[s - 1] = ti;
                        }
                    }
                }
            }
        }
        __syncthreads();
    }

    // dump per-thread top-8 lists, then 4-way merge per query
    #pragma unroll
    for (int k = 0; k < 8; ++k) {
        mD[(tq * 4 + sub) * 8 + k] = d8[k];
        mI[(tq * 4 + sub) * 8 + k] = i8[k];
    }
    __syncthreads();
    if (t < 64) {
        int p[4] = {0, 0, 0, 0};
        int outb = (b * 512 + qs + t) * 8;
        #pragma unroll 1
        for (int k = 0; k < 8; ++k) {
            float bd = 3.5e38f; int bi = 0x7fffffff; int bs = 0;
            #pragma unroll
            for (int s = 0; s < 4; ++s) {
                if (p[s] < 8) {
                    float dd = mD[(t * 4 + s) * 8 + p[s]];
                    int   ii = mI[(t * 4 + s) * 8 + p[s]];
                    if (dd < bd || (dd == bd && ii < bi)) { bd = dd; bi = ii; bs = s; }
                }
            }
            knn[outb + k] = bi;
            p[bs]++;
        }
    }
}

// ---------------------------------------------------------------------------
// MFMA fused 2-layer MLP.
// MODE 0: conv F=256 (A = [xi | xj] via split W1, K=512, 2 chunks of 256)
// MODE 1: conv layer1 F=6  (K=32, 1 chunk)
// MODE 2: m1 (A = Xcat row, K=1056, 3 chunks of 352), no max, out fp32
// Conv epilogue: hi->xcat slice, lo->xlo, fused squared-norm -> nrm.
// ---------------------------------------------------------------------------
template<int MODE>
__global__ __launch_bounds__(256, 3)
void mfma_mlp(const unsigned short* __restrict__ featbf, int fstride,
              const int* __restrict__ knn,
              const unsigned short* __restrict__ W1p, const float* __restrict__ B1,
              const unsigned short* __restrict__ W2p, const float* __restrict__ B2,
              float* __restrict__ outf,
              unsigned short* __restrict__ xcat, int sliceoff,
              unsigned short* __restrict__ xlo, float* __restrict__ nrm) {
    constexpr int NCHUNK  = (MODE == 0) ? 2 : (MODE == 1) ? 1 : 3;
    constexpr int KTPC    = (MODE == 0) ? 8 : (MODE == 1) ? 1 : 11;
    constexpr int ASTRIDE = (MODE == 0) ? 264 : (MODE == 1) ? 40 : 360;

    __shared__ unsigned short smem[64 * 360];
    __shared__ int rowi[64];
    __shared__ int rowj[64];

    const int t = threadIdx.x;
    const int l = t & 63, w = t >> 6;
    const int q = l >> 4, m16 = l & 15;

    if (MODE != 2 && t < 64) {
        int pt = blockIdx.x * 8 + (t >> 3);
        rowi[t] = pt;
        rowj[t] = (pt & ~511) + knn[pt * 8 + (t & 7)];
    }

    f32x4 acc1[21];
    #pragma unroll
    for (int i = 0; i < 21; ++i) acc1[i] = (f32x4){0.f, 0.f, 0.f, 0.f};

    for (int kc = 0; kc < NCHUNK; ++kc) {
        __syncthreads();
        if constexpr (MODE == 0) {
            const int r = t >> 2;
            const unsigned short* srow =
                featbf + (size_t)(kc == 0 ? rowi[r] : rowj[r]) * fstride;
            #pragma unroll
            for (int s = 0; s < 8; ++s) {
                int c16 = (t & 3) + (s << 2);
                *(uint4*)&smem[r * 264 + c16 * 8] = *(const uint4*)(srow + c16 * 8);
            }
        } else if constexpr (MODE == 1) {
            const int r = t >> 2, c16 = t & 3;
            const unsigned short* s2 =
                featbf + (size_t)(c16 < 2 ? rowi[r] : rowj[r]) * 16 + (c16 & 1) * 8;
            *(uint4*)&smem[r * 40 + c16 * 8] = *(const uint4*)s2;
        } else {
            const int r = t >> 2;
            const unsigned short* srow =
                featbf + (size_t)(blockIdx.x * 64 + r) * 1056 + kc * 352;
            #pragma unroll
            for (int s = 0; s < 11; ++s) {
                int c16 = (t & 3) + (s << 2);
                *(uint4*)&smem[r * 360 + c16 * 8] = *(const uint4*)(srow + c16 * 8);
            }
        }
        __syncthreads();

        const unsigned short* arow = &smem[(w * 16 + m16) * ASTRIDE + q * 8];
        #pragma unroll 1
        for (int kt = 0; kt < KTPC; ++kt) {
            bf16x8 af = *(const bf16x8*)(arow + kt * 32);
            const unsigned short* bp =
                W1p + ((size_t)(kc * KTPC + kt) * 21 * 64 + l) * 8;
            #pragma unroll
            for (int nt = 0; nt < 21; ++nt) {
                bf16x8 bf = *(const bf16x8*)(bp + nt * 512);
                acc1[nt] = __builtin_amdgcn_mfma_f32_16x16x32_bf16(af, bf, acc1[nt], 0, 0, 0);
            }
        }
    }
    __syncthreads();

    #pragma unroll
    for (int nt = 0; nt < 21; ++nt) {
        float b = B1[nt * 16 + m16];
        #pragma unroll
        for (int r = 0; r < 4; ++r) {
            float v = lrelu(acc1[nt][r] + b);
            smem[(w * 16 + q * 4 + r) * 360 + nt * 16 + m16] = f2bf(v);
        }
    }
    if (t < 64) {
        #pragma unroll
        for (int c = 336; c < 352; ++c) smem[t * 360 + c] = 0;
    }
    __syncthreads();

    f32x4 acc2[16];
    #pragma unroll
    for (int i = 0; i < 16; ++i) acc2[i] = (f32x4){0.f, 0.f, 0.f, 0.f};
    const unsigned short* hrow = &smem[(w * 16 + m16) * 360 + q * 8];
    #pragma unroll 1
    for (int kt = 0; kt < 11; ++kt) {
        bf16x8 af = *(const bf16x8*)(hrow + kt * 32);
        const unsigned short* bp = W2p + ((size_t)kt * 16 * 64 + l) * 8;
        #pragma unroll
        for (int nt = 0; nt < 16; ++nt) {
            bf16x8 bf = *(const bf16x8*)(bp + nt * 512);
            acc2[nt] = __builtin_amdgcn_mfma_f32_16x16x32_bf16(af, bf, acc2[nt], 0, 0, 0);
        }
    }

    if constexpr (MODE != 2) {
        // max over 8 edges, then hi/lo store + fused norm
        float nsum = 0.f;
        int p = blockIdx.x * 8 + w * 2 + (q >> 1);
        #pragma unroll
        for (int nt = 0; nt < 16; ++nt) {
            float b = B2[nt * 16 + m16];
            float mv = -3.4e38f;
            #pragma unroll
            for (int r = 0; r < 4; ++r) mv = fmaxf(mv, lrelu(acc2[nt][r] + b));
            mv = fmaxf(mv, __shfl_xor(mv, 16, 64));
            if ((q & 1) == 0) {
                int col = nt * 16 + m16;
                unsigned short hi = f2bf(mv);
                float fhi = bf2f(hi);
                unsigned short lo = f2bf(mv - fhi);
                float xr = fhi + bf2f(lo);
                nsum += xr * xr;
                xcat[(size_t)p * 1056 + sliceoff + col] = hi;
                xlo[(size_t)p * 256 + col] = lo;
            }
        }
        // reduce nsum across the 16 m16 lanes of this (w,q) group
        #pragma unroll
        for (int off = 1; off < 16; off <<= 1) nsum += __shfl_xor(nsum, off, 64);
        if ((q & 1) == 0 && m16 == 0) nrm[p] = nsum;
    } else {
        #pragma unroll
        for (int nt = 0; nt < 16; ++nt) {
            float b = B2[nt * 16 + m16];
            int col = nt * 16 + m16;
            #pragma unroll
            for (int r = 0; r < 4; ++r) {
                int p = blockIdx.x * 64 + w * 16 + q * 4 + r;
                outf[(size_t)p * 256 + col] = lrelu(acc2[nt][r] + b);
            }
        }
    }
}

// ---------------------------------------------------------------------------
__global__ __launch_bounds__(256) void pool_kernel(const float* __restrict__ h,
                                                   float* __restrict__ g) {
    int b = blockIdx.x, t = threadIdx.x;
    const float* hb = h + (size_t)b * 512 * 256;
    float s = 0.f;
    for (int n = 0; n < 512; ++n) s += hb[n * 256 + t];
    g[b * 256 + t] = s * (1.f / 512.f);
}

__global__ __launch_bounds__(128) void head_kernel(const float* __restrict__ g,
                                                   const float* __restrict__ w1,
                                                   const float* __restrict__ b1,
                                                   const float* __restrict__ w2,
                                                   const float* __restrict__ b2,
                                                   float* __restrict__ out) {
    __shared__ float gs[256];
    __shared__ float hid[128];
    int b = blockIdx.x, t = threadIdx.x;
    gs[t] = g[b * 256 + t];
    gs[t + 128] = g[b * 256 + t + 128];
    __syncthreads();
    float s = b1[t];
    for (int c = 0; c < 256; ++c) s += gs[c] * w1[c * 128 + t];
    hid[t] = lrelu(s);
    __syncthreads();
    if (t < 3) {
        float o = b2[t];
        for (int j = 0; j < 128; ++j) o += hid[j] * w2[j * 3 + t];
        out[b * 3 + t] = o;
    }
}

// ---------------------------------------------------------------------------
extern "C" void kernel_launch(void* const* d_in, const int* in_sizes, int n_in,
                              void* d_out, int out_size, void* d_ws, size_t ws_size,
                              hipStream_t stream) {
    const float* xb = (const float*)d_in[0];
    const float* c_w1[4] = { (const float*)d_in[3],  (const float*)d_in[7],
                             (const float*)d_in[11], (const float*)d_in[15] };
    const float* c_b1[4] = { (const float*)d_in[4],  (const float*)d_in[8],
                             (const float*)d_in[12], (const float*)d_in[16] };
    const float* c_w2[4] = { (const float*)d_in[5],  (const float*)d_in[9],
                             (const float*)d_in[13], (const float*)d_in[17] };
    const float* c_b2[4] = { (const float*)d_in[6],  (const float*)d_in[10],
                             (const float*)d_in[14], (const float*)d_in[18] };
    const float* m1w1 = (const float*)d_in[19];
    const float* m1b1 = (const float*)d_in[20];
    const float* m1w2 = (const float*)d_in[21];
    const float* m1b2 = (const float*)d_in[22];
    const float* m2w1 = (const float*)d_in[23];
    const float* m2b1 = (const float*)d_in[24];
    const float* m2w2 = (const float*)d_in[25];
    const float* m2b2 = (const float*)d_in[26];

    char* base = (char*)d_ws;
    size_t off = 0;
    auto alloc = [&](size_t bytes) { char* p = base + off; off = (off + bytes + 255) & ~(size_t)255; return p; };
    int*            knn   = (int*)           alloc((size_t)32768 * 8 * 4);
    float*          nrm   = (float*)         alloc((size_t)32768 * 4);
    float*          hm    = (float*)         alloc((size_t)32768 * 256 * 4);
    float*          g     = (float*)         alloc(64 * 256 * 4);
    unsigned short* xcat  = (unsigned short*)alloc((size_t)32768 * 1056 * 2);
    unsigned short* xlo   = (unsigned short*)alloc((size_t)32768 * 256 * 2);
    unsigned short* xbbf  = (unsigned short*)alloc((size_t)32768 * 16 * 2);
    unsigned short* w1p1  = (unsigned short*)alloc((size_t)1  * 21 * 512 * 2);
    unsigned short* w1p2  = (unsigned short*)alloc((size_t)16 * 21 * 512 * 2);
    unsigned short* w1p3  = (unsigned short*)alloc((size_t)16 * 21 * 512 * 2);
    unsigned short* w1p4  = (unsigned short*)alloc((size_t)16 * 21 * 512 * 2);
    unsigned short* w2p1  = (unsigned short*)alloc((size_t)11 * 16 * 512 * 2);
    unsigned short* w2p2  = (unsigned short*)alloc((size_t)11 * 16 * 512 * 2);
    unsigned short* w2p3  = (unsigned short*)alloc((size_t)11 * 16 * 512 * 2);
    unsigned short* w2p4  = (unsigned short*)alloc((size_t)11 * 16 * 512 * 2);
    unsigned short* m1p1  = (unsigned short*)alloc((size_t)33 * 21 * 512 * 2);
    unsigned short* m1p2  = (unsigned short*)alloc((size_t)11 * 16 * 512 * 2);

    PTable tb;
    tb.d[0] = { c_w1[0], w1p1, 1,  21, 336, 1, 16,  6,   0    };
    tb.d[1] = { c_w1[1], w1p2, 16, 21, 336, 1, 256, 256, 0    };
    tb.d[2] = { c_w1[2], w1p3, 16, 21, 336, 1, 256, 256, 0    };
    tb.d[3] = { c_w1[3], w1p4, 16, 21, 336, 1, 256, 256, 0    };
    tb.d[4] = { c_w2[0], w2p1, 11, 16, 256, 0, 0,   0,   336  };
    tb.d[5] = { c_w2[1], w2p2, 11, 16, 256, 0, 0,   0,   336  };
    tb.d[6] = { c_w2[2], w2p3, 11, 16, 256, 0, 0,   0,   336  };
    tb.d[7] = { c_w2[3], w2p4, 11, 16, 256, 0, 0,   0,   336  };
    tb.d[8] = { m1w1,    m1p1, 33, 21, 336, 2, 0,   0,   0    };
    tb.d[9] = { m1w2,    m1p2, 11, 16, 256, 0, 0,   0,   336  };
    pack_kernel<<<dim3(1386, 10), dim3(256), 0, stream>>>(tb);
    xbprep_kernel<<<128, 256, 0, stream>>>(xb, xbbf, xcat);

    // layer 1 (F=6): fp32 kNN on xb, then conv1 (writes hi/lo/norm of x1)
    norms_kernel<6><<<128, 256, 0, stream>>>(xb, nrm);
    knn_kernel<6><<<1024, 256, 0, stream>>>(xb, nrm, knn);
    mfma_mlp<1><<<4096, 256, 0, stream>>>(xbbf, 16, knn,
                                          w1p1, c_b1[0], w2p1, c_b2[0],
                                          nullptr, xcat, 32, xlo, nrm);

    // layers 2..4: MFMA kNN on (hi,lo) then conv
    unsigned short* w1ps[3] = { w1p2, w1p3, w1p4 };
    unsigned short* w2ps[3] = { w2p2, w2p3, w2p4 };
    for (int l = 1; l < 4; ++l) {
        int srcslice = 32 + (l - 1) * 256;
        int dstslice = 32 + l * 256;
        knn_mfma<<<512, 256, 0, stream>>>(xcat + srcslice, xlo, nrm, knn);
        mfma_mlp<0><<<4096, 256, 0, stream>>>(xcat + srcslice, 1056, knn,
                                              w1ps[l - 1], c_b1[l], w2ps[l - 1], c_b2[l],
                                              nullptr, xcat, dstslice, xlo, nrm);
    }

    // m1 over Xcat
    mfma_mlp<2><<<512, 256, 0, stream>>>(xcat, 1056, nullptr,
                                         m1p1, m1b1, m1p2, m1b2,
                                         hm, nullptr, 0, nullptr, nullptr);

    pool_kernel<<<64, 256, 0, stream>>>(hm, g);
    head_kernel<<<64, 128, 0, stream>>>(g, m2w1, m2b1, m2w2, m2b2, (float*)d_out);
}

// Round 6
// 1686.003 us; speedup vs baseline: 21.1140x; 1.0501x over previous
//
#include <hip/hip_runtime.h>
#include <hip/hip_bf16.h>

// B=64 graphs, N=512 pts, F0=6, K=8, conv out C=256, hidden H=336,
// m1 in 1030 (pad->1056), head 256->128->3.  fp32 in/out.
// Edge MLPs: bf16 MFMA, fp32 accum, wave-split-N + M=4 register blocking.
// kNN layers 2-4: bf16x3 MFMA Gram. Layer-1 kNN (F=6): fp32 VALU.

#define DEVFN __device__ __forceinline__
DEVFN float lrelu(float v) { return v >= 0.f ? v : 0.01f * v; }

using bf16x8 = __attribute__((ext_vector_type(8))) short;
using f32x4  = __attribute__((ext_vector_type(4))) float;

template<int N> struct IC { static constexpr int value = N; };

DEVFN unsigned short f2bf(float v) {
    __hip_bfloat16 h = __float2bfloat16(v);
    return *(unsigned short*)&h;
}
DEVFN float bf2f(unsigned short u) {
    return __uint_as_float((unsigned)u << 16);
}

// ---------------------------------------------------------------------------
// weight packing: fp32 [K][N] -> bf16 B-fragment layout [kt][nt][lane][8]
//   frag elem j of lane l = B[kt*32 + (l>>4)*8 + j][nt*16 + (l&15)]
// mode 0: plain, rows >= Ksrc zero (W2s)
// mode 1: conv W1 split: r<p1 -> src[r]-src[r+p1]; p0<=r<p0+p1 -> src[r-p0+p1]
// mode 2: m1 W1: r<6 -> src[r]; 32<=r -> src[r-26]; else 0
// ---------------------------------------------------------------------------
struct PDesc { const float* src; unsigned short* dst; int Kt, NT, N, mode, p0, p1, Ksrc; };
struct PTable { PDesc d[10]; };

__global__ __launch_bounds__(256) void pack_kernel(PTable tb) {
    PDesc d = tb.d[blockIdx.y];
    int i = blockIdx.x * 256 + threadIdx.x;
    int tot = d.Kt * d.NT * 512;
    if (i >= tot) return;
    int j = i & 7, lane = (i >> 3) & 63;
    int tile = i >> 9;
    int nt = tile % d.NT, kt = tile / d.NT;
    int k = kt * 32 + ((lane >> 4) << 3) + j;
    int n = nt * 16 + (lane & 15);
    float v = 0.f;
    if (d.mode == 0) {
        if (k < d.Ksrc) v = d.src[(size_t)k * d.N + n];
    } else if (d.mode == 1) {
        if (k < d.p1) v = d.src[(size_t)k * d.N + n] - d.src[(size_t)(k + d.p1) * d.N + n];
        else if (k >= d.p0 && k < d.p0 + d.p1) v = d.src[(size_t)(k - d.p0 + d.p1) * d.N + n];
    } else {
        if (k < 6) v = d.src[(size_t)k * d.N + n];
        else if (k >= 32 && k < 1056) v = d.src[(size_t)(k - 26) * d.N + n];
    }
    d.dst[i] = f2bf(v);
}

// ---------------------------------------------------------------------------
__global__ __launch_bounds__(256) void xbprep_kernel(const float* __restrict__ xb,
                                                     unsigned short* __restrict__ xbbf,
                                                     unsigned short* __restrict__ xcat) {
    int p = blockIdx.x * 256 + threadIdx.x;
    if (p >= 32768) return;
    unsigned short r[16];
    #pragma unroll
    for (int c = 0; c < 6; ++c) r[c] = f2bf(xb[p * 6 + c]);
    #pragma unroll
    for (int c = 6; c < 16; ++c) r[c] = 0;
    #pragma unroll
    for (int c = 0; c < 16; ++c) xbbf[p * 16 + c] = r[c];
    unsigned short* xc = xcat + (size_t)p * 1056;
    #pragma unroll
    for (int c = 0; c < 16; ++c) xc[c] = r[c];
    #pragma unroll
    for (int c = 16; c < 32; ++c) xc[c] = 0;
}

// ---------------------------------------------------------------------------
template<int F>
__global__ __launch_bounds__(256) void norms_kernel(const float* __restrict__ f,
                                                    float* __restrict__ nrm) {
    int p = blockIdx.x * 256 + threadIdx.x;
    if (p >= 64 * 512) return;
    const float* r = f + (size_t)p * F;
    float s = 0.f;
    #pragma unroll
    for (int i = 0; i < F; ++i) s += r[i] * r[i];
    nrm[p] = s;
}

// ---------------------------------------------------------------------------
// kNN fp32 (layer 1, F=6): 32 queries/block, stable top-8
// ---------------------------------------------------------------------------
template<int F>
__global__ __launch_bounds__(256) void knn_kernel(const float* __restrict__ feat,
                                                  const float* __restrict__ nrm,
                                                  int* __restrict__ knn) {
    constexpr int FP = (F == 6) ? 8 : (F + 4);
    __shared__ float Xq[32 * FP];
    __shared__ float Xc[32 * FP];
    __shared__ float qn[32], cn[32];
    __shared__ float dt[32 * 33];
    const int t  = threadIdx.x;
    const int b  = blockIdx.x >> 4;
    const int n0 = (blockIdx.x & 15) << 5;
    const float* fg = feat + (size_t)b * 512 * F;

    for (int i = t; i < 32 * F; i += 256) {
        int r = i / F, c = i - r * F;
        Xq[r * FP + c] = fg[(size_t)(n0 + r) * F + c];
    }
    if (t < 32) qn[t] = nrm[b * 512 + n0 + t];

    float d8[8]; int i8[8];
    #pragma unroll
    for (int k = 0; k < 8; ++k) { d8[k] = 3.4e38f; i8[k] = 0; }

    const int q = t >> 3, cs = t & 7;

    for (int ct = 0; ct < 16; ++ct) {
        const int c0 = ct << 5;
        __syncthreads();
        for (int i = t; i < 32 * F; i += 256) {
            int r = i / F, c = i - r * F;
            Xc[r * FP + c] = fg[(size_t)(c0 + r) * F + c];
        }
        if (t < 32) cn[t] = nrm[b * 512 + c0 + t];
        __syncthreads();

        float acc[4] = {0.f, 0.f, 0.f, 0.f};
        #pragma unroll
        for (int f = 0; f < F; ++f) {
            float qv = Xq[q * FP + f];
            #pragma unroll
            for (int j = 0; j < 4; ++j) acc[j] += qv * Xc[(cs + 8 * j) * FP + f];
        }
        #pragma unroll
        for (int j = 0; j < 4; ++j)
            dt[q * 33 + cs + 8 * j] = qn[q] + cn[cs + 8 * j] - 2.f * acc[j];
        __syncthreads();

        if (t < 32) {
            #pragma unroll 1
            for (int i = 0; i < 32; ++i) {
                float d = dt[t * 33 + i];
                if (d < d8[7]) {
                    d8[7] = d; i8[7] = c0 + i;
                    #pragma unroll
                    for (int s = 7; s >= 1; --s) {
                        if (d8[s] < d8[s - 1]) {
                            float td = d8[s]; d8[s] = d8[s - 1]; d8[s - 1] = td;
                            int   ti = i8[s]; i8[s] = i8[s - 1]; i8[s - 1] = ti;
                        }
                    }
                }
            }
        }
    }
    if (t < 32) {
        #pragma unroll
        for (int k = 0; k < 8; ++k)
            knn[((size_t)b * 512 + n0 + t) * 8 + k] = i8[k];
    }
}

// ---------------------------------------------------------------------------
// kNN via MFMA Gram (bf16x3): layers 2-4 (F=256).
// ---------------------------------------------------------------------------
__global__ __launch_bounds__(256, 2)
void knn_mfma(const unsigned short* __restrict__ xhi,  // stride 1056
              const unsigned short* __restrict__ xlo,  // stride 256
              const float* __restrict__ nrm,
              int* __restrict__ knn) {
    __shared__ unsigned short Qh[64 * 72], Ql[64 * 72], Ch[64 * 72], Cl[64 * 72];
    __shared__ float dt[64 * 66];
    __shared__ float qn[64], cn[64];
    float* mD = dt;
    int*   mI = (int*)(dt + 2048);

    const int t  = threadIdx.x;
    const int l  = t & 63, w = t >> 6;
    const int m16 = l & 15, q4 = l >> 4;
    const int b  = blockIdx.x >> 3;
    const int qs = (blockIdx.x & 7) << 6;

    if (t < 64) qn[t] = nrm[b * 512 + qs + t];

    float d8[8]; int i8[8];
    #pragma unroll
    for (int k = 0; k < 8; ++k) { d8[k] = 3.4e38f; i8[k] = 0x7fffffff; }

    const int sr = t >> 2;
    const int sc = (t & 3) << 4;
    const int tq = t & 63, sub = t >> 6;

    for (int cs = 0; cs < 8; ++cs) {
        const int c0 = cs << 6;
        if (t < 64) cn[t] = nrm[b * 512 + c0 + t];

        f32x4 acc[4];
        #pragma unroll
        for (int i = 0; i < 4; ++i) acc[i] = (f32x4){0.f, 0.f, 0.f, 0.f};

        for (int kc = 0; kc < 4; ++kc) {
            const int k0 = kc << 6;
            __syncthreads();
            {
                const unsigned short* qh = xhi + (size_t)(b * 512 + qs + sr) * 1056 + k0 + sc;
                const unsigned short* ql = xlo + (size_t)(b * 512 + qs + sr) * 256  + k0 + sc;
                const unsigned short* ch = xhi + (size_t)(b * 512 + c0 + sr) * 1056 + k0 + sc;
                const unsigned short* cl = xlo + (size_t)(b * 512 + c0 + sr) * 256  + k0 + sc;
                *(uint4*)&Qh[sr * 72 + sc]     = *(const uint4*)(qh);
                *(uint4*)&Qh[sr * 72 + sc + 8] = *(const uint4*)(qh + 8);
                *(uint4*)&Ql[sr * 72 + sc]     = *(const uint4*)(ql);
                *(uint4*)&Ql[sr * 72 + sc + 8] = *(const uint4*)(ql + 8);
                *(uint4*)&Ch[sr * 72 + sc]     = *(const uint4*)(ch);
                *(uint4*)&Ch[sr * 72 + sc + 8] = *(const uint4*)(ch + 8);
                *(uint4*)&Cl[sr * 72 + sc]     = *(const uint4*)(cl);
                *(uint4*)&Cl[sr * 72 + sc + 8] = *(const uint4*)(cl + 8);
            }
            __syncthreads();

            #pragma unroll
            for (int kt = 0; kt < 2; ++kt) {
                const int ko = kt * 32 + q4 * 8;
                bf16x8 ah = *(const bf16x8*)&Qh[(w * 16 + m16) * 72 + ko];
                bf16x8 al = *(const bf16x8*)&Ql[(w * 16 + m16) * 72 + ko];
                #pragma unroll
                for (int nt = 0; nt < 4; ++nt) {
                    bf16x8 bh = *(const bf16x8*)&Ch[(nt * 16 + m16) * 72 + ko];
                    bf16x8 bl = *(const bf16x8*)&Cl[(nt * 16 + m16) * 72 + ko];
                    acc[nt] = __builtin_amdgcn_mfma_f32_16x16x32_bf16(ah, bh, acc[nt], 0, 0, 0);
                    acc[nt] = __builtin_amdgcn_mfma_f32_16x16x32_bf16(ah, bl, acc[nt], 0, 0, 0);
                    acc[nt] = __builtin_amdgcn_mfma_f32_16x16x32_bf16(al, bh, acc[nt], 0, 0, 0);
                }
            }
        }

        #pragma unroll
        for (int nt = 0; nt < 4; ++nt) {
            float cv = cn[nt * 16 + m16];
            #pragma unroll
            for (int rr = 0; rr < 4; ++rr) {
                int qr = w * 16 + q4 * 4 + rr;
                dt[qr * 66 + nt * 16 + m16] = qn[qr] + cv - 2.f * acc[nt][rr];
            }
        }
        __syncthreads();

        {
            const float* drow = &dt[tq * 66 + sub * 16];
            #pragma unroll 1
            for (int j = 0; j < 16; ++j) {
                float d = drow[j];
                if (d < d8[7]) {
                    d8[7] = d; i8[7] = c0 + sub * 16 + j;
                    #pragma unroll
                    for (int s = 7; s >= 1; --s) {
                        if (d8[s] < d8[s - 1]) {
                            float td = d8[s]; d8[s] = d8[s - 1]; d8[s - 1] = td;
                            int   ti = i8[s]; i8[s] = i8[s - 1]; i8[s - 1] = ti;
                        }
                    }
                }
            }
        }
        __syncthreads();
    }

    #pragma unroll
    for (int k = 0; k < 8; ++k) {
        mD[(tq * 4 + sub) * 8 + k] = d8[k];
        mI[(tq * 4 + sub) * 8 + k] = i8[k];
    }
    __syncthreads();
    if (t < 64) {
        int p[4] = {0, 0, 0, 0};
        int outb = (b * 512 + qs + t) * 8;
        #pragma unroll 1
        for (int k = 0; k < 8; ++k) {
            float bd = 3.5e38f; int bi = 0x7fffffff; int bs = 0;
            #pragma unroll
            for (int s = 0; s < 4; ++s) {
                if (p[s] < 8) {
                    float dd = mD[(t * 4 + s) * 8 + p[s]];
                    int   ii = mI[(t * 4 + s) * 8 + p[s]];
                    if (dd < bd || (dd == bd && ii < bi)) { bd = dd; bi = ii; bs = s; }
                }
            }
            knn[outb + k] = bi;
            p[bs]++;
        }
    }
}

// ---------------------------------------------------------------------------
// MFMA fused 2-layer MLP, wave-split-N, M=4 register blocking.
// Each wave: all 64 rows x its N-slice. GEMM1 ntiles {6,6,6,3}; GEMM2 4 each.
// MODE 0: conv F=256 (split W1, K=512, 2 chunks). MODE 1: conv1 (K=32).
// MODE 2: m1 (K=1056, 3 chunks), fp32 out, no max.
// ---------------------------------------------------------------------------
template<int MODE>
__global__ __launch_bounds__(256, 3)
void mfma_mlp(const unsigned short* __restrict__ featbf, int fstride,
              const int* __restrict__ knn,
              const unsigned short* __restrict__ W1p, const float* __restrict__ B1,
              const unsigned short* __restrict__ W2p, const float* __restrict__ B2,
              float* __restrict__ outf,
              unsigned short* __restrict__ xcat, int sliceoff,
              unsigned short* __restrict__ xlo, float* __restrict__ nrm) {
    constexpr int NCHUNK  = (MODE == 0) ? 2 : (MODE == 1) ? 1 : 3;
    constexpr int KTPC    = (MODE == 0) ? 8 : (MODE == 1) ? 1 : 11;
    constexpr int ASTRIDE = (MODE == 0) ? 264 : (MODE == 1) ? 40 : 360;

    __shared__ unsigned short smem[64 * 360];
    __shared__ int rowi[64];
    __shared__ int rowj[64];
    __shared__ float nparts[8][4];

    const int t = threadIdx.x;
    const int l = t & 63, w = t >> 6;
    const int q4 = l >> 4, m16 = l & 15;
    const int s1 = w * 6;          // GEMM1 ntile start (21 total: 6,6,6,3)
    const int s2 = w * 4;          // GEMM2 ntile start (16 total)

    if (MODE != 2 && t < 64) {
        int pt = blockIdx.x * 8 + (t >> 3);
        rowi[t] = pt;
        rowj[t] = (pt & ~511) + knn[pt * 8 + (t & 7)];
    }

    f32x4 acc1[4][6];
    #pragma unroll
    for (int mt = 0; mt < 4; ++mt)
        #pragma unroll
        for (int n = 0; n < 6; ++n) acc1[mt][n] = (f32x4){0.f, 0.f, 0.f, 0.f};

    // GEMM1 inner loop over one staged chunk, templated on ntile count
    auto g1 = [&](auto c1c, int ktbase) {
        constexpr int C1 = decltype(c1c)::value;
        #pragma unroll 1
        for (int kt = 0; kt < KTPC; ++kt) {
            bf16x8 af[4];
            #pragma unroll
            for (int mt = 0; mt < 4; ++mt)
                af[mt] = *(const bf16x8*)&smem[(mt * 16 + m16) * ASTRIDE + q4 * 8 + kt * 32];
            const unsigned short* bp =
                W1p + ((size_t)((ktbase + kt) * 21 + s1) * 64 + l) * 8;
            #pragma unroll
            for (int n = 0; n < C1; ++n) {
                bf16x8 bf = *(const bf16x8*)(bp + n * 512);
                #pragma unroll
                for (int mt = 0; mt < 4; ++mt)
                    acc1[mt][n] = __builtin_amdgcn_mfma_f32_16x16x32_bf16(af[mt], bf, acc1[mt][n], 0, 0, 0);
            }
        }
    };

    for (int kc = 0; kc < NCHUNK; ++kc) {
        __syncthreads();
        if constexpr (MODE == 0) {
            const int r = t >> 2;
            const unsigned short* srow =
                featbf + (size_t)(kc == 0 ? rowi[r] : rowj[r]) * fstride;
            #pragma unroll
            for (int s = 0; s < 8; ++s) {
                int c16 = (t & 3) + (s << 2);
                *(uint4*)&smem[r * 264 + c16 * 8] = *(const uint4*)(srow + c16 * 8);
            }
        } else if constexpr (MODE == 1) {
            const int r = t >> 2, c16 = t & 3;
            const unsigned short* s2p =
                featbf + (size_t)(c16 < 2 ? rowi[r] : rowj[r]) * 16 + (c16 & 1) * 8;
            *(uint4*)&smem[r * 40 + c16 * 8] = *(const uint4*)s2p;
        } else {
            const int r = t >> 2;
            const unsigned short* srow =
                featbf + (size_t)(blockIdx.x * 64 + r) * 1056 + kc * 352;
            #pragma unroll
            for (int s = 0; s < 11; ++s) {
                int c16 = (t & 3) + (s << 2);
                *(uint4*)&smem[r * 360 + c16 * 8] = *(const uint4*)(srow + c16 * 8);
            }
        }
        __syncthreads();

        if (w < 3) g1(IC<6>{}, kc * KTPC);
        else       g1(IC<3>{}, kc * KTPC);
    }
    __syncthreads();

    // h1 = lrelu(acc1 + b1) -> bf16 LDS [64][360]; cols 336..351 zero-padded
    {
        const int c1 = (w < 3) ? 6 : 3;
        for (int n = 0; n < c1; ++n) {
            int nt = s1 + n;
            float b = B1[nt * 16 + m16];
            #pragma unroll
            for (int mt = 0; mt < 4; ++mt)
                #pragma unroll
                for (int r = 0; r < 4; ++r) {
                    float v = lrelu(acc1[mt][n][r] + b);
                    smem[(mt * 16 + q4 * 4 + r) * 360 + nt * 16 + m16] = f2bf(v);
                }
        }
    }
    if (t < 64) {
        #pragma unroll
        for (int c = 336; c < 352; ++c) smem[t * 360 + c] = 0;
    }
    __syncthreads();

    // GEMM2: h1[64][352] x W2 slice (4 ntiles per wave)
    f32x4 acc2[4][4];
    #pragma unroll
    for (int mt = 0; mt < 4; ++mt)
        #pragma unroll
        for (int n = 0; n < 4; ++n) acc2[mt][n] = (f32x4){0.f, 0.f, 0.f, 0.f};
    #pragma unroll 1
    for (int kt = 0; kt < 11; ++kt) {
        bf16x8 af[4];
        #pragma unroll
        for (int mt = 0; mt < 4; ++mt)
            af[mt] = *(const bf16x8*)&smem[(mt * 16 + m16) * 360 + q4 * 8 + kt * 32];
        const unsigned short* bp = W2p + ((size_t)(kt * 16 + s2) * 64 + l) * 8;
        #pragma unroll
        for (int n = 0; n < 4; ++n) {
            bf16x8 bf = *(const bf16x8*)(bp + n * 512);
            #pragma unroll
            for (int mt = 0; mt < 4; ++mt)
                acc2[mt][n] = __builtin_amdgcn_mfma_f32_16x16x32_bf16(af[mt], bf, acc2[mt][n], 0, 0, 0);
        }
    }

    if constexpr (MODE != 2) {
        // max over 8 edges; wave owns 64 cols of every point in the block
        #pragma unroll
        for (int mt = 0; mt < 4; ++mt) {
            float nsum = 0.f;
            int plocal = mt * 2 + (q4 >> 1);
            int p = blockIdx.x * 8 + plocal;
            #pragma unroll
            for (int n = 0; n < 4; ++n) {
                int nt = s2 + n;
                float b = B2[nt * 16 + m16];
                float mv = -3.4e38f;
                #pragma unroll
                for (int r = 0; r < 4; ++r) mv = fmaxf(mv, lrelu(acc2[mt][n][r] + b));
                mv = fmaxf(mv, __shfl_xor(mv, 16, 64));
                if ((q4 & 1) == 0) {
                    int col = nt * 16 + m16;
                    unsigned short hi = f2bf(mv);
                    float fhi = bf2f(hi);
                    unsigned short lo = f2bf(mv - fhi);
                    float xr = fhi + bf2f(lo);
                    nsum += xr * xr;
                    xcat[(size_t)p * 1056 + sliceoff + col] = hi;
                    xlo[(size_t)p * 256 + col] = lo;
                }
            }
            #pragma unroll
            for (int o = 1; o < 16; o <<= 1) nsum += __shfl_xor(nsum, o, 64);
            if ((q4 & 1) == 0 && m16 == 0) nparts[plocal][w] = nsum;
        }
        __syncthreads();
        if (t < 8)
            nrm[blockIdx.x * 8 + t] =
                nparts[t][0] + nparts[t][1] + nparts[t][2] + nparts[t][3];
    } else {
        #pragma unroll
        for (int mt = 0; mt < 4; ++mt)
            #pragma unroll
            for (int n = 0; n < 4; ++n) {
                int nt = s2 + n;
                float b = B2[nt * 16 + m16];
                int col = nt * 16 + m16;
                #pragma unroll
                for (int r = 0; r < 4; ++r) {
                    int p = blockIdx.x * 64 + mt * 16 + q4 * 4 + r;
                    outf[(size_t)p * 256 + col] = lrelu(acc2[mt][n][r] + b);
                }
            }
    }
}

// ---------------------------------------------------------------------------
__global__ __launch_bounds__(256) void pool_kernel(const float* __restrict__ h,
                                                   float* __restrict__ g) {
    int b = blockIdx.x, t = threadIdx.x;
    const float* hb = h + (size_t)b * 512 * 256;
    float s = 0.f;
    for (int n = 0; n < 512; ++n) s += hb[n * 256 + t];
    g[b * 256 + t] = s * (1.f / 512.f);
}

__global__ __launch_bounds__(128) void head_kernel(const float* __restrict__ g,
                                                   const float* __restrict__ w1,
                                                   const float* __restrict__ b1,
                                                   const float* __restrict__ w2,
                                                   const float* __restrict__ b2,
                                                   float* __restrict__ out) {
    __shared__ float gs[256];
    __shared__ float hid[128];
    int b = blockIdx.x, t = threadIdx.x;
    gs[t] = g[b * 256 + t];
    gs[t + 128] = g[b * 256 + t + 128];
    __syncthreads();
    float s = b1[t];
    for (int c = 0; c < 256; ++c) s += gs[c] * w1[c * 128 + t];
    hid[t] = lrelu(s);
    __syncthreads();
    if (t < 3) {
        float o = b2[t];
        for (int j = 0; j < 128; ++j) o += hid[j] * w2[j * 3 + t];
        out[b * 3 + t] = o;
    }
}

// ---------------------------------------------------------------------------
extern "C" void kernel_launch(void* const* d_in, const int* in_sizes, int n_in,
                              void* d_out, int out_size, void* d_ws, size_t ws_size,
                              hipStream_t stream) {
    const float* xb = (const float*)d_in[0];
    const float* c_w1[4] = { (const float*)d_in[3],  (const float*)d_in[7],
                             (const float*)d_in[11], (const float*)d_in[15] };
    const float* c_b1[4] = { (const float*)d_in[4],  (const float*)d_in[8],
                             (const float*)d_in[12], (const float*)d_in[16] };
    const float* c_w2[4] = { (const float*)d_in[5],  (const float*)d_in[9],
                             (const float*)d_in[13], (const float*)d_in[17] };
    const float* c_b2[4] = { (const float*)d_in[6],  (const float*)d_in[10],
                             (const float*)d_in[14], (const float*)d_in[18] };
    const float* m1w1 = (const float*)d_in[19];
    const float* m1b1 = (const float*)d_in[20];
    const float* m1w2 = (const float*)d_in[21];
    const float* m1b2 = (const float*)d_in[22];
    const float* m2w1 = (const float*)d_in[23];
    const float* m2b1 = (const float*)d_in[24];
    const float* m2w2 = (const float*)d_in[25];
    const float* m2b2 = (const float*)d_in[26];

    char* base = (char*)d_ws;
    size_t off = 0;
    auto alloc = [&](size_t bytes) { char* p = base + off; off = (off + bytes + 255) & ~(size_t)255; return p; };
    int*            knn   = (int*)           alloc((size_t)32768 * 8 * 4);
    float*          nrm   = (float*)         alloc((size_t)32768 * 4);
    float*          hm    = (float*)         alloc((size_t)32768 * 256 * 4);
    float*          g     = (float*)         alloc(64 * 256 * 4);
    unsigned short* xcat  = (unsigned short*)alloc((size_t)32768 * 1056 * 2);
    unsigned short* xlo   = (unsigned short*)alloc((size_t)32768 * 256 * 2);
    unsigned short* xbbf  = (unsigned short*)alloc((size_t)32768 * 16 * 2);
    unsigned short* w1p1  = (unsigned short*)alloc((size_t)1  * 21 * 512 * 2);
    unsigned short* w1p2  = (unsigned short*)alloc((size_t)16 * 21 * 512 * 2);
    unsigned short* w1p3  = (unsigned short*)alloc((size_t)16 * 21 * 512 * 2);
    unsigned short* w1p4  = (unsigned short*)alloc((size_t)16 * 21 * 512 * 2);
    unsigned short* w2p1  = (unsigned short*)alloc((size_t)11 * 16 * 512 * 2);
    unsigned short* w2p2  = (unsigned short*)alloc((size_t)11 * 16 * 512 * 2);
    unsigned short* w2p3  = (unsigned short*)alloc((size_t)11 * 16 * 512 * 2);
    unsigned short* w2p4  = (unsigned short*)alloc((size_t)11 * 16 * 512 * 2);
    unsigned short* m1p1  = (unsigned short*)alloc((size_t)33 * 21 * 512 * 2);
    unsigned short* m1p2  = (unsigned short*)alloc((size_t)11 * 16 * 512 * 2);

    PTable tb;
    tb.d[0] = { c_w1[0], w1p1, 1,  21, 336, 1, 16,  6,   0    };
    tb.d[1] = { c_w1[1], w1p2, 16, 21, 336, 1, 256, 256, 0    };
    tb.d[2] = { c_w1[2], w1p3, 16, 21, 336, 1, 256, 256, 0    };
    tb.d[3] = { c_w1[3], w1p4, 16, 21, 336, 1, 256, 256, 0    };
    tb.d[4] = { c_w2[0], w2p1, 11, 16, 256, 0, 0,   0,   336  };
    tb.d[5] = { c_w2[1], w2p2, 11, 16, 256, 0, 0,   0,   336  };
    tb.d[6] = { c_w2[2], w2p3, 11, 16, 256, 0, 0,   0,   336  };
    tb.d[7] = { c_w2[3], w2p4, 11, 16, 256, 0, 0,   0,   336  };
    tb.d[8] = { m1w1,    m1p1, 33, 21, 336, 2, 0,   0,   0    };
    tb.d[9] = { m1w2,    m1p2, 11, 16, 256, 0, 0,   0,   336  };
    pack_kernel<<<dim3(1386, 10), dim3(256), 0, stream>>>(tb);
    xbprep_kernel<<<128, 256, 0, stream>>>(xb, xbbf, xcat);

    // layer 1 (F=6): fp32 kNN on xb, conv1 writes hi/lo/norm of x1
    norms_kernel<6><<<128, 256, 0, stream>>>(xb, nrm);
    knn_kernel<6><<<1024, 256, 0, stream>>>(xb, nrm, knn);
    mfma_mlp<1><<<4096, 256, 0, stream>>>(xbbf, 16, knn,
                                          w1p1, c_b1[0], w2p1, c_b2[0],
                                          nullptr, xcat, 32, xlo, nrm);

    // layers 2..4: MFMA kNN on (hi,lo) then conv
    unsigned short* w1ps[3] = { w1p2, w1p3, w1p4 };
    unsigned short* w2ps[3] = { w2p2, w2p3, w2p4 };
    for (int l = 1; l < 4; ++l) {
        int srcslice = 32 + (l - 1) * 256;
        int dstslice = 32 + l * 256;
        knn_mfma<<<512, 256, 0, stream>>>(xcat + srcslice, xlo, nrm, knn);
        mfma_mlp<0><<<4096, 256, 0, stream>>>(xcat + srcslice, 1056, knn,
                                              w1ps[l - 1], c_b1[l], w2ps[l - 1], c_b2[l],
                                              nullptr, xcat, dstslice, xlo, nrm);
    }

    // m1 over Xcat
    mfma_mlp<2><<<512, 256, 0, stream>>>(xcat, 1056, nullptr,
                                         m1p1, m1b1, m1p2, m1b2,
                                         hm, nullptr, 0, nullptr, nullptr);

    pool_kernel<<<64, 256, 0, stream>>>(hm, g);
    head_kernel<<<64, 128, 0, stream>>>(g, m2w1, m2b1, m2w2, m2b2, (float*)d_out);
}

// Round 7
// 1662.808 us; speedup vs baseline: 21.4085x; 1.0139x over previous
//
#include <hip/hip_runtime.h>
#include <hip/hip_bf16.h>

// B=64 graphs, N=512 pts, F0=6, K=8, conv out C=256, hidden H=336,
// m1 in 1030 (pad->1056), head 256->128->3.  fp32 in/out.
// Edge MLPs: bf16 MFMA, fp32 accum, wave-split-N + M=4 register blocking.
// Features live in compact xfl[p][512] (hi|lo interleaved, 1KB rows) for
// gather/kNN; xcat[p][1056] holds the m1 concat. All epilogue stores are
// LDS-staged and written as full-line uint4 bursts (R6 showed 34x RMW
// amplification from scattered 2-B stores).

#define DEVFN __device__ __forceinline__
DEVFN float lrelu(float v) { return v >= 0.f ? v : 0.01f * v; }

using bf16x8 = __attribute__((ext_vector_type(8))) short;
using f32x4  = __attribute__((ext_vector_type(4))) float;

template<int N> struct IC { static constexpr int value = N; };

DEVFN unsigned short f2bf(float v) {
    __hip_bfloat16 h = __float2bfloat16(v);
    return *(unsigned short*)&h;
}
DEVFN float bf2f(unsigned short u) {
    return __uint_as_float((unsigned)u << 16);
}

// ---------------------------------------------------------------------------
// weight packing: fp32 [K][N] -> bf16 B-fragment layout [kt][nt][lane][8]
// ---------------------------------------------------------------------------
struct PDesc { const float* src; unsigned short* dst; int Kt, NT, N, mode, p0, p1, Ksrc; };
struct PTable { PDesc d[10]; };

__global__ __launch_bounds__(256) void pack_kernel(PTable tb) {
    PDesc d = tb.d[blockIdx.y];
    int i = blockIdx.x * 256 + threadIdx.x;
    int tot = d.Kt * d.NT * 512;
    if (i >= tot) return;
    int j = i & 7, lane = (i >> 3) & 63;
    int tile = i >> 9;
    int nt = tile % d.NT, kt = tile / d.NT;
    int k = kt * 32 + ((lane >> 4) << 3) + j;
    int n = nt * 16 + (lane & 15);
    float v = 0.f;
    if (d.mode == 0) {
        if (k < d.Ksrc) v = d.src[(size_t)k * d.N + n];
    } else if (d.mode == 1) {
        if (k < d.p1) v = d.src[(size_t)k * d.N + n] - d.src[(size_t)(k + d.p1) * d.N + n];
        else if (k >= d.p0 && k < d.p0 + d.p1) v = d.src[(size_t)(k - d.p0 + d.p1) * d.N + n];
    } else {
        if (k < 6) v = d.src[(size_t)k * d.N + n];
        else if (k >= 32 && k < 1056) v = d.src[(size_t)(k - 26) * d.N + n];
    }
    d.dst[i] = f2bf(v);
}

// ---------------------------------------------------------------------------
__global__ __launch_bounds__(256) void xbprep_kernel(const float* __restrict__ xb,
                                                     unsigned short* __restrict__ xbbf,
                                                     unsigned short* __restrict__ xcat) {
    int p = blockIdx.x * 256 + threadIdx.x;
    if (p >= 32768) return;
    unsigned short r[16];
    #pragma unroll
    for (int c = 0; c < 6; ++c) r[c] = f2bf(xb[p * 6 + c]);
    #pragma unroll
    for (int c = 6; c < 16; ++c) r[c] = 0;
    #pragma unroll
    for (int c = 0; c < 16; ++c) xbbf[p * 16 + c] = r[c];
    unsigned short* xc = xcat + (size_t)p * 1056;
    #pragma unroll
    for (int c = 0; c < 16; ++c) xc[c] = r[c];
    #pragma unroll
    for (int c = 16; c < 32; ++c) xc[c] = 0;
}

// ---------------------------------------------------------------------------
template<int F>
__global__ __launch_bounds__(256) void norms_kernel(const float* __restrict__ f,
                                                    float* __restrict__ nrm) {
    int p = blockIdx.x * 256 + threadIdx.x;
    if (p >= 64 * 512) return;
    const float* r = f + (size_t)p * F;
    float s = 0.f;
    #pragma unroll
    for (int i = 0; i < F; ++i) s += r[i] * r[i];
    nrm[p] = s;
}

// ---------------------------------------------------------------------------
// kNN fp32 (layer 1, F=6): 32 queries/block, stable top-8
// ---------------------------------------------------------------------------
template<int F>
__global__ __launch_bounds__(256) void knn_kernel(const float* __restrict__ feat,
                                                  const float* __restrict__ nrm,
                                                  int* __restrict__ knn) {
    constexpr int FP = (F == 6) ? 8 : (F + 4);
    __shared__ float Xq[32 * FP];
    __shared__ float Xc[32 * FP];
    __shared__ float qn[32], cn[32];
    __shared__ float dt[32 * 33];
    const int t  = threadIdx.x;
    const int b  = blockIdx.x >> 4;
    const int n0 = (blockIdx.x & 15) << 5;
    const float* fg = feat + (size_t)b * 512 * F;

    for (int i = t; i < 32 * F; i += 256) {
        int r = i / F, c = i - r * F;
        Xq[r * FP + c] = fg[(size_t)(n0 + r) * F + c];
    }
    if (t < 32) qn[t] = nrm[b * 512 + n0 + t];

    float d8[8]; int i8[8];
    #pragma unroll
    for (int k = 0; k < 8; ++k) { d8[k] = 3.4e38f; i8[k] = 0; }

    const int q = t >> 3, cs = t & 7;

    for (int ct = 0; ct < 16; ++ct) {
        const int c0 = ct << 5;
        __syncthreads();
        for (int i = t; i < 32 * F; i += 256) {
            int r = i / F, c = i - r * F;
            Xc[r * FP + c] = fg[(size_t)(c0 + r) * F + c];
        }
        if (t < 32) cn[t] = nrm[b * 512 + c0 + t];
        __syncthreads();

        float acc[4] = {0.f, 0.f, 0.f, 0.f};
        #pragma unroll
        for (int f = 0; f < F; ++f) {
            float qv = Xq[q * FP + f];
            #pragma unroll
            for (int j = 0; j < 4; ++j) acc[j] += qv * Xc[(cs + 8 * j) * FP + f];
        }
        #pragma unroll
        for (int j = 0; j < 4; ++j)
            dt[q * 33 + cs + 8 * j] = qn[q] + cn[cs + 8 * j] - 2.f * acc[j];
        __syncthreads();

        if (t < 32) {
            #pragma unroll 1
            for (int i = 0; i < 32; ++i) {
                float d = dt[t * 33 + i];
                if (d < d8[7]) {
                    d8[7] = d; i8[7] = c0 + i;
                    #pragma unroll
                    for (int s = 7; s >= 1; --s) {
                        if (d8[s] < d8[s - 1]) {
                            float td = d8[s]; d8[s] = d8[s - 1]; d8[s - 1] = td;
                            int   ti = i8[s]; i8[s] = i8[s - 1]; i8[s - 1] = ti;
                        }
                    }
                }
            }
        }
    }
    if (t < 32) {
        #pragma unroll
        for (int k = 0; k < 8; ++k)
            knn[((size_t)b * 512 + n0 + t) * 8 + k] = i8[k];
    }
}

// ---------------------------------------------------------------------------
// kNN via MFMA Gram (bf16x3), layers 2-4. Reads xfl (hi|lo, stride 512).
// ---------------------------------------------------------------------------
__global__ __launch_bounds__(256, 2)
void knn_mfma(const unsigned short* __restrict__ xfl,
              const float* __restrict__ nrm,
              int* __restrict__ knn) {
    __shared__ unsigned short Qh[64 * 72], Ql[64 * 72], Ch[64 * 72], Cl[64 * 72];
    __shared__ float dt[64 * 66];
    __shared__ float qn[64], cn[64];
    float* mD = dt;
    int*   mI = (int*)(dt + 2048);

    const int t  = threadIdx.x;
    const int l  = t & 63, w = t >> 6;
    const int m16 = l & 15, q4 = l >> 4;
    const int b  = blockIdx.x >> 3;
    const int qs = (blockIdx.x & 7) << 6;

    if (t < 64) qn[t] = nrm[b * 512 + qs + t];

    float d8[8]; int i8[8];
    #pragma unroll
    for (int k = 0; k < 8; ++k) { d8[k] = 3.4e38f; i8[k] = 0x7fffffff; }

    const int sr = t >> 2;
    const int sc = (t & 3) << 4;
    const int tq = t & 63, sub = t >> 6;

    for (int cs = 0; cs < 8; ++cs) {
        const int c0 = cs << 6;
        if (t < 64) cn[t] = nrm[b * 512 + c0 + t];

        f32x4 acc[4];
        #pragma unroll
        for (int i = 0; i < 4; ++i) acc[i] = (f32x4){0.f, 0.f, 0.f, 0.f};

        for (int kc = 0; kc < 4; ++kc) {
            const int k0 = kc << 6;
            __syncthreads();
            {
                const unsigned short* qr = xfl + (size_t)(b * 512 + qs + sr) * 512;
                const unsigned short* cr = xfl + (size_t)(b * 512 + c0 + sr) * 512;
                *(uint4*)&Qh[sr * 72 + sc]     = *(const uint4*)(qr + k0 + sc);
                *(uint4*)&Qh[sr * 72 + sc + 8] = *(const uint4*)(qr + k0 + sc + 8);
                *(uint4*)&Ql[sr * 72 + sc]     = *(const uint4*)(qr + 256 + k0 + sc);
                *(uint4*)&Ql[sr * 72 + sc + 8] = *(const uint4*)(qr + 256 + k0 + sc + 8);
                *(uint4*)&Ch[sr * 72 + sc]     = *(const uint4*)(cr + k0 + sc);
                *(uint4*)&Ch[sr * 72 + sc + 8] = *(const uint4*)(cr + k0 + sc + 8);
                *(uint4*)&Cl[sr * 72 + sc]     = *(const uint4*)(cr + 256 + k0 + sc);
                *(uint4*)&Cl[sr * 72 + sc + 8] = *(const uint4*)(cr + 256 + k0 + sc + 8);
            }
            __syncthreads();

            #pragma unroll
            for (int kt = 0; kt < 2; ++kt) {
                const int ko = kt * 32 + q4 * 8;
                bf16x8 ah = *(const bf16x8*)&Qh[(w * 16 + m16) * 72 + ko];
                bf16x8 al = *(const bf16x8*)&Ql[(w * 16 + m16) * 72 + ko];
                #pragma unroll
                for (int nt = 0; nt < 4; ++nt) {
                    bf16x8 bh = *(const bf16x8*)&Ch[(nt * 16 + m16) * 72 + ko];
                    bf16x8 bl = *(const bf16x8*)&Cl[(nt * 16 + m16) * 72 + ko];
                    acc[nt] = __builtin_amdgcn_mfma_f32_16x16x32_bf16(ah, bh, acc[nt], 0, 0, 0);
                    acc[nt] = __builtin_amdgcn_mfma_f32_16x16x32_bf16(ah, bl, acc[nt], 0, 0, 0);
                    acc[nt] = __builtin_amdgcn_mfma_f32_16x16x32_bf16(al, bh, acc[nt], 0, 0, 0);
                }
            }
        }

        #pragma unroll
        for (int nt = 0; nt < 4; ++nt) {
            float cv = cn[nt * 16 + m16];
            #pragma unroll
            for (int rr = 0; rr < 4; ++rr) {
                int qr = w * 16 + q4 * 4 + rr;
                dt[qr * 66 + nt * 16 + m16] = qn[qr] + cv - 2.f * acc[nt][rr];
            }
        }
        __syncthreads();

        {
            const float* drow = &dt[tq * 66 + sub * 16];
            #pragma unroll 1
            for (int j = 0; j < 16; ++j) {
                float d = drow[j];
                if (d < d8[7]) {
                    d8[7] = d; i8[7] = c0 + sub * 16 + j;
                    #pragma unroll
                    for (int s = 7; s >= 1; --s) {
                        if (d8[s] < d8[s - 1]) {
                            float td = d8[s]; d8[s] = d8[s - 1]; d8[s - 1] = td;
                            int   ti = i8[s]; i8[s] = i8[s - 1]; i8[s - 1] = ti;
                        }
                    }
                }
            }
        }
        __syncthreads();
    }

    #pragma unroll
    for (int k = 0; k < 8; ++k) {
        mD[(tq * 4 + sub) * 8 + k] = d8[k];
        mI[(tq * 4 + sub) * 8 + k] = i8[k];
    }
    __syncthreads();
    if (t < 64) {
        int p[4] = {0, 0, 0, 0};
        int outb = (b * 512 + qs + t) * 8;
        #pragma unroll 1
        for (int k = 0; k < 8; ++k) {
            float bd = 3.5e38f; int bi = 0x7fffffff; int bs = 0;
            #pragma unroll
            for (int s = 0; s < 4; ++s) {
                if (p[s] < 8) {
                    float dd = mD[(t * 4 + s) * 8 + p[s]];
                    int   ii = mI[(t * 4 + s) * 8 + p[s]];
                    if (dd < bd || (dd == bd && ii < bi)) { bd = dd; bi = ii; bs = s; }
                }
            }
            knn[outb + k] = bi;
            p[bs]++;
        }
    }
}

// ---------------------------------------------------------------------------
// MFMA fused 2-layer MLP, wave-split-N, M=4 register blocking.
// MODE 0: conv F=256 (A from xfl hi, stride 512). MODE 1: conv1 (K=32).
// MODE 2: m1 (K=1056 from xcat), fp32 out, no max.
// Conv epilogue: hi|lo staged in LDS then full-line uint4 stores to xfl and
// the xcat slice; fused squared-norm -> nrm.
// ---------------------------------------------------------------------------
template<int MODE>
__global__ __launch_bounds__(256, 3)
void mfma_mlp(const unsigned short* __restrict__ featbf,
              const int* __restrict__ knn,
              const unsigned short* __restrict__ W1p, const float* __restrict__ B1,
              const unsigned short* __restrict__ W2p, const float* __restrict__ B2,
              float* __restrict__ outf,
              unsigned short* __restrict__ xcat, int sliceoff,
              unsigned short* __restrict__ xfl, float* __restrict__ nrm) {
    constexpr int NCHUNK  = (MODE == 0) ? 2 : (MODE == 1) ? 1 : 3;
    constexpr int KTPC    = (MODE == 0) ? 8 : (MODE == 1) ? 1 : 11;
    constexpr int ASTRIDE = (MODE == 0) ? 264 : (MODE == 1) ? 40 : 360;

    __shared__ unsigned short smem[64 * 360];
    __shared__ int rowi[64];
    __shared__ int rowj[64];
    __shared__ float nparts[8][4];

    const int t = threadIdx.x;
    const int l = t & 63, w = t >> 6;
    const int q4 = l >> 4, m16 = l & 15;
    const int s1 = w * 6;          // GEMM1 ntile start (21 total: 6,6,6,3)
    const int s2 = w * 4;          // GEMM2 ntile start (16 total)

    if (MODE != 2 && t < 64) {
        int pt = blockIdx.x * 8 + (t >> 3);
        rowi[t] = pt;
        rowj[t] = (pt & ~511) + knn[pt * 8 + (t & 7)];
    }

    f32x4 acc1[4][6];
    #pragma unroll
    for (int mt = 0; mt < 4; ++mt)
        #pragma unroll
        for (int n = 0; n < 6; ++n) acc1[mt][n] = (f32x4){0.f, 0.f, 0.f, 0.f};

    auto g1 = [&](auto c1c, int ktbase) {
        constexpr int C1 = decltype(c1c)::value;
        #pragma unroll 1
        for (int kt = 0; kt < KTPC; ++kt) {
            bf16x8 af[4];
            #pragma unroll
            for (int mt = 0; mt < 4; ++mt)
                af[mt] = *(const bf16x8*)&smem[(mt * 16 + m16) * ASTRIDE + q4 * 8 + kt * 32];
            const unsigned short* bp =
                W1p + ((size_t)((ktbase + kt) * 21 + s1) * 64 + l) * 8;
            #pragma unroll
            for (int n = 0; n < C1; ++n) {
                bf16x8 bf = *(const bf16x8*)(bp + n * 512);
                #pragma unroll
                for (int mt = 0; mt < 4; ++mt)
                    acc1[mt][n] = __builtin_amdgcn_mfma_f32_16x16x32_bf16(af[mt], bf, acc1[mt][n], 0, 0, 0);
            }
        }
    };

    for (int kc = 0; kc < NCHUNK; ++kc) {
        __syncthreads();
        if constexpr (MODE == 0) {
            const int r = t >> 2;
            const unsigned short* srow =
                featbf + (size_t)(kc == 0 ? rowi[r] : rowj[r]) * 512;
            #pragma unroll
            for (int s = 0; s < 8; ++s) {
                int c16 = (t & 3) + (s << 2);
                *(uint4*)&smem[r * 264 + c16 * 8] = *(const uint4*)(srow + c16 * 8);
            }
        } else if constexpr (MODE == 1) {
            const int r = t >> 2, c16 = t & 3;
            const unsigned short* s2p =
                featbf + (size_t)(c16 < 2 ? rowi[r] : rowj[r]) * 16 + (c16 & 1) * 8;
            *(uint4*)&smem[r * 40 + c16 * 8] = *(const uint4*)s2p;
        } else {
            const int r = t >> 2;
            const unsigned short* srow =
                featbf + (size_t)(blockIdx.x * 64 + r) * 1056 + kc * 352;
            #pragma unroll
            for (int s = 0; s < 11; ++s) {
                int c16 = (t & 3) + (s << 2);
                *(uint4*)&smem[r * 360 + c16 * 8] = *(const uint4*)(srow + c16 * 8);
            }
        }
        __syncthreads();

        if (w < 3) g1(IC<6>{}, kc * KTPC);
        else       g1(IC<3>{}, kc * KTPC);
    }
    __syncthreads();

    // h1 = lrelu(acc1 + b1) -> bf16 LDS [64][360]; cols 336..351 zero-padded
    {
        const int c1 = (w < 3) ? 6 : 3;
        for (int n = 0; n < c1; ++n) {
            int nt = s1 + n;
            float b = B1[nt * 16 + m16];
            #pragma unroll
            for (int mt = 0; mt < 4; ++mt)
                #pragma unroll
                for (int r = 0; r < 4; ++r) {
                    float v = lrelu(acc1[mt][n][r] + b);
                    smem[(mt * 16 + q4 * 4 + r) * 360 + nt * 16 + m16] = f2bf(v);
                }
        }
    }
    if (t < 64) {
        #pragma unroll
        for (int c = 336; c < 352; ++c) smem[t * 360 + c] = 0;
    }
    __syncthreads();

    // GEMM2: h1[64][352] x W2 slice (4 ntiles per wave)
    f32x4 acc2[4][4];
    #pragma unroll
    for (int mt = 0; mt < 4; ++mt)
        #pragma unroll
        for (int n = 0; n < 4; ++n) acc2[mt][n] = (f32x4){0.f, 0.f, 0.f, 0.f};
    #pragma unroll 1
    for (int kt = 0; kt < 11; ++kt) {
        bf16x8 af[4];
        #pragma unroll
        for (int mt = 0; mt < 4; ++mt)
            af[mt] = *(const bf16x8*)&smem[(mt * 16 + m16) * 360 + q4 * 8 + kt * 32];
        const unsigned short* bp = W2p + ((size_t)(kt * 16 + s2) * 64 + l) * 8;
        #pragma unroll
        for (int n = 0; n < 4; ++n) {
            bf16x8 bf = *(const bf16x8*)(bp + n * 512);
            #pragma unroll
            for (int mt = 0; mt < 4; ++mt)
                acc2[mt][n] = __builtin_amdgcn_mfma_f32_16x16x32_bf16(af[mt], bf, acc2[mt][n], 0, 0, 0);
        }
    }

    if constexpr (MODE != 2) {
        // max over 8 edges -> stage hi|lo into LDS (smem reused; barrier first)
        __syncthreads();
        unsigned short* sh = smem;          // [8][512]: cols 0..255 hi, 256..511 lo
        #pragma unroll
        for (int mt = 0; mt < 4; ++mt) {
            float nsum = 0.f;
            int plocal = mt * 2 + (q4 >> 1);
            #pragma unroll
            for (int n = 0; n < 4; ++n) {
                int nt = s2 + n;
                float b = B2[nt * 16 + m16];
                float mv = -3.4e38f;
                #pragma unroll
                for (int r = 0; r < 4; ++r) mv = fmaxf(mv, lrelu(acc2[mt][n][r] + b));
                mv = fmaxf(mv, __shfl_xor(mv, 16, 64));
                if ((q4 & 1) == 0) {
                    int col = nt * 16 + m16;
                    unsigned short hi = f2bf(mv);
                    float fhi = bf2f(hi);
                    unsigned short lo = f2bf(mv - fhi);
                    float xr = fhi + bf2f(lo);
                    nsum += xr * xr;
                    sh[plocal * 512 + col] = hi;
                    sh[plocal * 512 + 256 + col] = lo;
                }
            }
            #pragma unroll
            for (int o = 1; o < 16; o <<= 1) nsum += __shfl_xor(nsum, o, 64);
            if ((q4 & 1) == 0 && m16 == 0) nparts[plocal][w] = nsum;
        }
        __syncthreads();
        // coalesced stores: 32 threads per point row, 2 uint4 each
        {
            int r = t >> 5, cb = (t & 31) * 16;
            int p = blockIdx.x * 8 + r;
            uint4 v0 = *(uint4*)&sh[r * 512 + cb];
            uint4 v1 = *(uint4*)&sh[r * 512 + cb + 8];
            *(uint4*)&xfl[(size_t)p * 512 + cb]     = v0;
            *(uint4*)&xfl[(size_t)p * 512 + cb + 8] = v1;
            if (cb < 256) {
                *(uint4*)&xcat[(size_t)p * 1056 + sliceoff + cb]     = v0;
                *(uint4*)&xcat[(size_t)p * 1056 + sliceoff + cb + 8] = v1;
            }
        }
        if (t < 8)
            nrm[blockIdx.x * 8 + t] =
                nparts[t][0] + nparts[t][1] + nparts[t][2] + nparts[t][3];
    } else {
        #pragma unroll
        for (int mt = 0; mt < 4; ++mt)
            #pragma unroll
            for (int n = 0; n < 4; ++n) {
                int nt = s2 + n;
                float b = B2[nt * 16 + m16];
                int col = nt * 16 + m16;
                #pragma unroll
                for (int r = 0; r < 4; ++r) {
                    int p = blockIdx.x * 64 + mt * 16 + q4 * 4 + r;
                    outf[(size_t)p * 256 + col] = lrelu(acc2[mt][n][r] + b);
                }
            }
    }
}

// ---------------------------------------------------------------------------
__global__ __launch_bounds__(256) void pool_kernel(const float* __restrict__ h,
                                                   float* __restrict__ g) {
    int b = blockIdx.x, t = threadIdx.x;
    const float* hb = h + (size_t)b * 512 * 256;
    float s = 0.f;
    for (int n = 0; n < 512; ++n) s += hb[n * 256 + t];
    g[b * 256 + t] = s * (1.f / 512.f);
}

__global__ __launch_bounds__(128) void head_kernel(const float* __restrict__ g,
                                                   const float* __restrict__ w1,
                                                   const float* __restrict__ b1,
                                                   const float* __restrict__ w2,
                                                   const float* __restrict__ b2,
                                                   float* __restrict__ out) {
    __shared__ float gs[256];
    __shared__ float hid[128];
    int b = blockIdx.x, t = threadIdx.x;
    gs[t] = g[b * 256 + t];
    gs[t + 128] = g[b * 256 + t + 128];
    __syncthreads();
    float s = b1[t];
    for (int c = 0; c < 256; ++c) s += gs[c] * w1[c * 128 + t];
    hid[t] = lrelu(s);
    __syncthreads();
    if (t < 3) {
        float o = b2[t];
        for (int j = 0; j < 128; ++j) o += hid[j] * w2[j * 3 + t];
        out[b * 3 + t] = o;
    }
}

// ---------------------------------------------------------------------------
extern "C" void kernel_launch(void* const* d_in, const int* in_sizes, int n_in,
                              void* d_out, int out_size, void* d_ws, size_t ws_size,
                              hipStream_t stream) {
    const float* xb = (const float*)d_in[0];
    const float* c_w1[4] = { (const float*)d_in[3],  (const float*)d_in[7],
                             (const float*)d_in[11], (const float*)d_in[15] };
    const float* c_b1[4] = { (const float*)d_in[4],  (const float*)d_in[8],
                             (const float*)d_in[12], (const float*)d_in[16] };
    const float* c_w2[4] = { (const float*)d_in[5],  (const float*)d_in[9],
                             (const float*)d_in[13], (const float*)d_in[17] };
    const float* c_b2[4] = { (const float*)d_in[6],  (const float*)d_in[10],
                             (const float*)d_in[14], (const float*)d_in[18] };
    const float* m1w1 = (const float*)d_in[19];
    const float* m1b1 = (const float*)d_in[20];
    const float* m1w2 = (const float*)d_in[21];
    const float* m1b2 = (const float*)d_in[22];
    const float* m2w1 = (const float*)d_in[23];
    const float* m2b1 = (const float*)d_in[24];
    const float* m2w2 = (const float*)d_in[25];
    const float* m2b2 = (const float*)d_in[26];

    char* base = (char*)d_ws;
    size_t off = 0;
    auto alloc = [&](size_t bytes) { char* p = base + off; off = (off + bytes + 255) & ~(size_t)255; return p; };
    int*            knn   = (int*)           alloc((size_t)32768 * 8 * 4);
    float*          nrm   = (float*)         alloc((size_t)32768 * 4);
    float*          hm    = (float*)         alloc((size_t)32768 * 256 * 4);
    float*          g     = (float*)         alloc(64 * 256 * 4);
    unsigned short* xcat  = (unsigned short*)alloc((size_t)32768 * 1056 * 2);
    unsigned short* xfl   = (unsigned short*)alloc((size_t)32768 * 512 * 2);
    unsigned short* xbbf  = (unsigned short*)alloc((size_t)32768 * 16 * 2);
    unsigned short* w1p1  = (unsigned short*)alloc((size_t)1  * 21 * 512 * 2);
    unsigned short* w1p2  = (unsigned short*)alloc((size_t)16 * 21 * 512 * 2);
    unsigned short* w1p3  = (unsigned short*)alloc((size_t)16 * 21 * 512 * 2);
    unsigned short* w1p4  = (unsigned short*)alloc((size_t)16 * 21 * 512 * 2);
    unsigned short* w2p1  = (unsigned short*)alloc((size_t)11 * 16 * 512 * 2);
    unsigned short* w2p2  = (unsigned short*)alloc((size_t)11 * 16 * 512 * 2);
    unsigned short* w2p3  = (unsigned short*)alloc((size_t)11 * 16 * 512 * 2);
    unsigned short* w2p4  = (unsigned short*)alloc((size_t)11 * 16 * 512 * 2);
    unsigned short* m1p1  = (unsigned short*)alloc((size_t)33 * 21 * 512 * 2);
    unsigned short* m1p2  = (unsigned short*)alloc((size_t)11 * 16 * 512 * 2);

    PTable tb;
    tb.d[0] = { c_w1[0], w1p1, 1,  21, 336, 1, 16,  6,   0    };
    tb.d[1] = { c_w1[1], w1p2, 16, 21, 336, 1, 256, 256, 0    };
    tb.d[2] = { c_w1[2], w1p3, 16, 21, 336, 1, 256, 256, 0    };
    tb.d[3] = { c_w1[3], w1p4, 16, 21, 336, 1, 256, 256, 0    };
    tb.d[4] = { c_w2[0], w2p1, 11, 16, 256, 0, 0,   0,   336  };
    tb.d[5] = { c_w2[1], w2p2, 11, 16, 256, 0, 0,   0,   336  };
    tb.d[6] = { c_w2[2], w2p3, 11, 16, 256, 0, 0,   0,   336  };
    tb.d[7] = { c_w2[3], w2p4, 11, 16, 256, 0, 0,   0,   336  };
    tb.d[8] = { m1w1,    m1p1, 33, 21, 336, 2, 0,   0,   0    };
    tb.d[9] = { m1w2,    m1p2, 11, 16, 256, 0, 0,   0,   336  };
    pack_kernel<<<dim3(1386, 10), dim3(256), 0, stream>>>(tb);
    xbprep_kernel<<<128, 256, 0, stream>>>(xb, xbbf, xcat);

    // layer 1 (F=6): fp32 kNN on xb, conv1 writes xfl/xcat-slice/norm of x1
    norms_kernel<6><<<128, 256, 0, stream>>>(xb, nrm);
    knn_kernel<6><<<1024, 256, 0, stream>>>(xb, nrm, knn);
    mfma_mlp<1><<<4096, 256, 0, stream>>>(xbbf, knn,
                                          w1p1, c_b1[0], w2p1, c_b2[0],
                                          nullptr, xcat, 32, xfl, nrm);

    // layers 2..4: MFMA kNN on xfl then conv
    unsigned short* w1ps[3] = { w1p2, w1p3, w1p4 };
    unsigned short* w2ps[3] = { w2p2, w2p3, w2p4 };
    for (int l = 1; l < 4; ++l) {
        int dstslice = 32 + l * 256;
        knn_mfma<<<512, 256, 0, stream>>>(xfl, nrm, knn);
        mfma_mlp<0><<<4096, 256, 0, stream>>>(xfl, knn,
                                              w1ps[l - 1], c_b1[l], w2ps[l - 1], c_b2[l],
                                              nullptr, xcat, dstslice, xfl, nrm);
    }

    // m1 over Xcat
    mfma_mlp<2><<<512, 256, 0, stream>>>(xcat, nullptr,
                                         m1p1, m1b1, m1p2, m1b2,
                                         hm, nullptr, 0, nullptr, nullptr);

    pool_kernel<<<64, 256, 0, stream>>>(hm, g);
    head_kernel<<<64, 128, 0, stream>>>(g, m2w1, m2b1, m2w2, m2b2, (float*)d_out);
}

// Round 8
// 1550.629 us; speedup vs baseline: 22.9573x; 1.0723x over previous
//
#include <hip/hip_runtime.h>
#include <hip/hip_bf16.h>

// B=64 graphs, N=512 pts, F0=6, K=8, conv out C=256, hidden H=336,
// m1 in 1030 (pad->1056), head 256->128->3.  fp32 in/out.
// Edge MLPs: bf16 MFMA, fp32 accum, wave-split-N + M=4 register blocking.
// R8: xi-factorization — P = xi@W1a computed once per POINT (pgemm), conv
// GEMM1 only does xj@W1b (K=256, one chunk); P added in the h1 epilogue.

#define DEVFN __device__ __forceinline__
DEVFN float lrelu(float v) { return v >= 0.f ? v : 0.01f * v; }

using bf16x8 = __attribute__((ext_vector_type(8))) short;
using f32x4  = __attribute__((ext_vector_type(4))) float;

template<int N> struct IC { static constexpr int value = N; };

DEVFN unsigned short f2bf(float v) {
    __hip_bfloat16 h = __float2bfloat16(v);
    return *(unsigned short*)&h;
}
DEVFN float bf2f(unsigned short u) {
    return __uint_as_float((unsigned)u << 16);
}

// ---------------------------------------------------------------------------
// weight packing: fp32 [K][N] -> bf16 B-fragment layout [kt][nt][lane][8]
// mode 0: plain, rows >= Ksrc zero (W2s)
// mode 1: diff rows: k<p1 -> src[k]-src[k+p1]; else p0<=k<p0+p1 -> src[k-p0+p1]
// mode 2: m1 W1: k<6 -> src[k]; 32<=k -> src[k-26]; else 0
// mode 3: plain with row offset p0: src[k+p0]
// ---------------------------------------------------------------------------
struct PDesc { const float* src; unsigned short* dst; int Kt, NT, N, mode, p0, p1, Ksrc; };
struct PTable { PDesc d[13]; };

__global__ __launch_bounds__(256) void pack_kernel(PTable tb) {
    PDesc d = tb.d[blockIdx.y];
    int i = blockIdx.x * 256 + threadIdx.x;
    int tot = d.Kt * d.NT * 512;
    if (i >= tot) return;
    int j = i & 7, lane = (i >> 3) & 63;
    int tile = i >> 9;
    int nt = tile % d.NT, kt = tile / d.NT;
    int k = kt * 32 + ((lane >> 4) << 3) + j;
    int n = nt * 16 + (lane & 15);
    float v = 0.f;
    if (d.mode == 0) {
        if (k < d.Ksrc) v = d.src[(size_t)k * d.N + n];
    } else if (d.mode == 1) {
        if (k < d.p1) v = d.src[(size_t)k * d.N + n] - d.src[(size_t)(k + d.p1) * d.N + n];
        else if (k >= d.p0 && k < d.p0 + d.p1) v = d.src[(size_t)(k - d.p0 + d.p1) * d.N + n];
    } else if (d.mode == 2) {
        if (k < 6) v = d.src[(size_t)k * d.N + n];
        else if (k >= 32 && k < 1056) v = d.src[(size_t)(k - 26) * d.N + n];
    } else {
        v = d.src[(size_t)(k + d.p0) * d.N + n];
    }
    d.dst[i] = f2bf(v);
}

// ---------------------------------------------------------------------------
__global__ __launch_bounds__(256) void xbprep_kernel(const float* __restrict__ xb,
                                                     unsigned short* __restrict__ xbbf,
                                                     unsigned short* __restrict__ xcat) {
    int p = blockIdx.x * 256 + threadIdx.x;
    if (p >= 32768) return;
    unsigned short r[16];
    #pragma unroll
    for (int c = 0; c < 6; ++c) r[c] = f2bf(xb[p * 6 + c]);
    #pragma unroll
    for (int c = 6; c < 16; ++c) r[c] = 0;
    #pragma unroll
    for (int c = 0; c < 16; ++c) xbbf[p * 16 + c] = r[c];
    unsigned short* xc = xcat + (size_t)p * 1056;
    #pragma unroll
    for (int c = 0; c < 16; ++c) xc[c] = r[c];
    #pragma unroll
    for (int c = 16; c < 32; ++c) xc[c] = 0;
}

// ---------------------------------------------------------------------------
template<int F>
__global__ __launch_bounds__(256) void norms_kernel(const float* __restrict__ f,
                                                    float* __restrict__ nrm) {
    int p = blockIdx.x * 256 + threadIdx.x;
    if (p >= 64 * 512) return;
    const float* r = f + (size_t)p * F;
    float s = 0.f;
    #pragma unroll
    for (int i = 0; i < F; ++i) s += r[i] * r[i];
    nrm[p] = s;
}

// ---------------------------------------------------------------------------
// kNN fp32 (layer 1, F=6): 32 queries/block, stable top-8
// ---------------------------------------------------------------------------
template<int F>
__global__ __launch_bounds__(256) void knn_kernel(const float* __restrict__ feat,
                                                  const float* __restrict__ nrm,
                                                  int* __restrict__ knn) {
    constexpr int FP = (F == 6) ? 8 : (F + 4);
    __shared__ float Xq[32 * FP];
    __shared__ float Xc[32 * FP];
    __shared__ float qn[32], cn[32];
    __shared__ float dt[32 * 33];
    const int t  = threadIdx.x;
    const int b  = blockIdx.x >> 4;
    const int n0 = (blockIdx.x & 15) << 5;
    const float* fg = feat + (size_t)b * 512 * F;

    for (int i = t; i < 32 * F; i += 256) {
        int r = i / F, c = i - r * F;
        Xq[r * FP + c] = fg[(size_t)(n0 + r) * F + c];
    }
    if (t < 32) qn[t] = nrm[b * 512 + n0 + t];

    float d8[8]; int i8[8];
    #pragma unroll
    for (int k = 0; k < 8; ++k) { d8[k] = 3.4e38f; i8[k] = 0; }

    const int q = t >> 3, cs = t & 7;

    for (int ct = 0; ct < 16; ++ct) {
        const int c0 = ct << 5;
        __syncthreads();
        for (int i = t; i < 32 * F; i += 256) {
            int r = i / F, c = i - r * F;
            Xc[r * FP + c] = fg[(size_t)(c0 + r) * F + c];
        }
        if (t < 32) cn[t] = nrm[b * 512 + c0 + t];
        __syncthreads();

        float acc[4] = {0.f, 0.f, 0.f, 0.f};
        #pragma unroll
        for (int f = 0; f < F; ++f) {
            float qv = Xq[q * FP + f];
            #pragma unroll
            for (int j = 0; j < 4; ++j) acc[j] += qv * Xc[(cs + 8 * j) * FP + f];
        }
        #pragma unroll
        for (int j = 0; j < 4; ++j)
            dt[q * 33 + cs + 8 * j] = qn[q] + cn[cs + 8 * j] - 2.f * acc[j];
        __syncthreads();

        if (t < 32) {
            #pragma unroll 1
            for (int i = 0; i < 32; ++i) {
                float d = dt[t * 33 + i];
                if (d < d8[7]) {
                    d8[7] = d; i8[7] = c0 + i;
                    #pragma unroll
                    for (int s = 7; s >= 1; --s) {
                        if (d8[s] < d8[s - 1]) {
                            float td = d8[s]; d8[s] = d8[s - 1]; d8[s - 1] = td;
                            int   ti = i8[s]; i8[s] = i8[s - 1]; i8[s - 1] = ti;
                        }
                    }
                }
            }
        }
    }
    if (t < 32) {
        #pragma unroll
        for (int k = 0; k < 8; ++k)
            knn[((size_t)b * 512 + n0 + t) * 8 + k] = i8[k];
    }
}

// ---------------------------------------------------------------------------
// kNN via MFMA Gram (bf16x3), layers 2-4. Reads xfl (hi|lo, stride 512).
// ---------------------------------------------------------------------------
__global__ __launch_bounds__(256, 2)
void knn_mfma(const unsigned short* __restrict__ xfl,
              const float* __restrict__ nrm,
              int* __restrict__ knn) {
    __shared__ unsigned short Qh[64 * 72], Ql[64 * 72], Ch[64 * 72], Cl[64 * 72];
    __shared__ float dt[64 * 66];
    __shared__ float qn[64], cn[64];
    float* mD = dt;
    int*   mI = (int*)(dt + 2048);

    const int t  = threadIdx.x;
    const int l  = t & 63, w = t >> 6;
    const int m16 = l & 15, q4 = l >> 4;
    const int b  = blockIdx.x >> 3;
    const int qs = (blockIdx.x & 7) << 6;

    if (t < 64) qn[t] = nrm[b * 512 + qs + t];

    float d8[8]; int i8[8];
    #pragma unroll
    for (int k = 0; k < 8; ++k) { d8[k] = 3.4e38f; i8[k] = 0x7fffffff; }

    const int sr = t >> 2;
    const int sc = (t & 3) << 4;
    const int tq = t & 63, sub = t >> 6;

    for (int cs = 0; cs < 8; ++cs) {
        const int c0 = cs << 6;
        if (t < 64) cn[t] = nrm[b * 512 + c0 + t];

        f32x4 acc[4];
        #pragma unroll
        for (int i = 0; i < 4; ++i) acc[i] = (f32x4){0.f, 0.f, 0.f, 0.f};

        for (int kc = 0; kc < 4; ++kc) {
            const int k0 = kc << 6;
            __syncthreads();
            {
                const unsigned short* qr = xfl + (size_t)(b * 512 + qs + sr) * 512;
                const unsigned short* cr = xfl + (size_t)(b * 512 + c0 + sr) * 512;
                *(uint4*)&Qh[sr * 72 + sc]     = *(const uint4*)(qr + k0 + sc);
                *(uint4*)&Qh[sr * 72 + sc + 8] = *(const uint4*)(qr + k0 + sc + 8);
                *(uint4*)&Ql[sr * 72 + sc]     = *(const uint4*)(qr + 256 + k0 + sc);
                *(uint4*)&Ql[sr * 72 + sc + 8] = *(const uint4*)(qr + 256 + k0 + sc + 8);
                *(uint4*)&Ch[sr * 72 + sc]     = *(const uint4*)(cr + k0 + sc);
                *(uint4*)&Ch[sr * 72 + sc + 8] = *(const uint4*)(cr + k0 + sc + 8);
                *(uint4*)&Cl[sr * 72 + sc]     = *(const uint4*)(cr + 256 + k0 + sc);
                *(uint4*)&Cl[sr * 72 + sc + 8] = *(const uint4*)(cr + 256 + k0 + sc + 8);
            }
            __syncthreads();

            #pragma unroll
            for (int kt = 0; kt < 2; ++kt) {
                const int ko = kt * 32 + q4 * 8;
                bf16x8 ah = *(const bf16x8*)&Qh[(w * 16 + m16) * 72 + ko];
                bf16x8 al = *(const bf16x8*)&Ql[(w * 16 + m16) * 72 + ko];
                #pragma unroll
                for (int nt = 0; nt < 4; ++nt) {
                    bf16x8 bh = *(const bf16x8*)&Ch[(nt * 16 + m16) * 72 + ko];
                    bf16x8 bl = *(const bf16x8*)&Cl[(nt * 16 + m16) * 72 + ko];
                    acc[nt] = __builtin_amdgcn_mfma_f32_16x16x32_bf16(ah, bh, acc[nt], 0, 0, 0);
                    acc[nt] = __builtin_amdgcn_mfma_f32_16x16x32_bf16(ah, bl, acc[nt], 0, 0, 0);
                    acc[nt] = __builtin_amdgcn_mfma_f32_16x16x32_bf16(al, bh, acc[nt], 0, 0, 0);
                }
            }
        }

        #pragma unroll
        for (int nt = 0; nt < 4; ++nt) {
            float cv = cn[nt * 16 + m16];
            #pragma unroll
            for (int rr = 0; rr < 4; ++rr) {
                int qr = w * 16 + q4 * 4 + rr;
                dt[qr * 66 + nt * 16 + m16] = qn[qr] + cv - 2.f * acc[nt][rr];
            }
        }
        __syncthreads();

        {
            const float* drow = &dt[tq * 66 + sub * 16];
            #pragma unroll 1
            for (int j = 0; j < 16; ++j) {
                float d = drow[j];
                if (d < d8[7]) {
                    d8[7] = d; i8[7] = c0 + sub * 16 + j;
                    #pragma unroll
                    for (int s = 7; s >= 1; --s) {
                        if (d8[s] < d8[s - 1]) {
                            float td = d8[s]; d8[s] = d8[s - 1]; d8[s - 1] = td;
                            int   ti = i8[s]; i8[s] = i8[s - 1]; i8[s - 1] = ti;
                        }
                    }
                }
            }
        }
        __syncthreads();
    }

    #pragma unroll
    for (int k = 0; k < 8; ++k) {
        mD[(tq * 4 + sub) * 8 + k] = d8[k];
        mI[(tq * 4 + sub) * 8 + k] = i8[k];
    }
    __syncthreads();
    if (t < 64) {
        int p[4] = {0, 0, 0, 0};
        int outb = (b * 512 + qs + t) * 8;
        #pragma unroll 1
        for (int k = 0; k < 8; ++k) {
            float bd = 3.5e38f; int bi = 0x7fffffff; int bs = 0;
            #pragma unroll
            for (int s = 0; s < 4; ++s) {
                if (p[s] < 8) {
                    float dd = mD[(t * 4 + s) * 8 + p[s]];
                    int   ii = mI[(t * 4 + s) * 8 + p[s]];
                    if (dd < bd || (dd == bd && ii < bi)) { bd = dd; bi = ii; bs = s; }
                }
            }
            knn[outb + k] = bi;
            p[bs]++;
        }
    }
}

// ---------------------------------------------------------------------------
// Point-GEMM: P = x_hi @ W1a  (32768 x 336, K=256), 64 points/block.
// ---------------------------------------------------------------------------
__global__ __launch_bounds__(256, 3)
void pgemm_kernel(const unsigned short* __restrict__ xfl,
                  const unsigned short* __restrict__ W1ap,
                  float* __restrict__ Pp) {
    __shared__ unsigned short smem[64 * 264];
    const int t = threadIdx.x;
    const int l = t & 63, w = t >> 6;
    const int q4 = l >> 4, m16 = l & 15;
    const int s1 = w * 6;

    // stage 64 point rows (hi half, 512 B each)
    {
        const int r = t >> 2;
        const unsigned short* srow = xfl + (size_t)(blockIdx.x * 64 + r) * 512;
        #pragma unroll
        for (int s = 0; s < 8; ++s) {
            int c16 = (t & 3) + (s << 2);
            *(uint4*)&smem[r * 264 + c16 * 8] = *(const uint4*)(srow + c16 * 8);
        }
    }
    __syncthreads();

    f32x4 acc[4][6];
    #pragma unroll
    for (int mt = 0; mt < 4; ++mt)
        #pragma unroll
        for (int n = 0; n < 6; ++n) acc[mt][n] = (f32x4){0.f, 0.f, 0.f, 0.f};

    auto run = [&](auto c1c) {
        constexpr int C1 = decltype(c1c)::value;
        #pragma unroll 1
        for (int kt = 0; kt < 8; ++kt) {
            bf16x8 af[4];
            #pragma unroll
            for (int mt = 0; mt < 4; ++mt)
                af[mt] = *(const bf16x8*)&smem[(mt * 16 + m16) * 264 + q4 * 8 + kt * 32];
            const unsigned short* bp = W1ap + ((size_t)(kt * 21 + s1) * 64 + l) * 8;
            #pragma unroll
            for (int n = 0; n < C1; ++n) {
                bf16x8 bf = *(const bf16x8*)(bp + n * 512);
                #pragma unroll
                for (int mt = 0; mt < 4; ++mt)
                    acc[mt][n] = __builtin_amdgcn_mfma_f32_16x16x32_bf16(af[mt], bf, acc[mt][n], 0, 0, 0);
            }
        }
    };
    if (w < 3) run(IC<6>{});
    else       run(IC<3>{});

    const int c1 = (w < 3) ? 6 : 3;
    for (int n = 0; n < c1; ++n) {
        int col = (s1 + n) * 16 + m16;
        #pragma unroll
        for (int mt = 0; mt < 4; ++mt)
            #pragma unroll
            for (int r = 0; r < 4; ++r) {
                int p = blockIdx.x * 64 + mt * 16 + q4 * 4 + r;
                Pp[(size_t)p * 336 + col] = acc[mt][n][r];
            }
    }
}

// ---------------------------------------------------------------------------
// MFMA fused 2-layer MLP, wave-split-N, M=4 register blocking.
// MODE 0: conv F=256, GEMM1 = xj@W1b only (K=256, 1 chunk); P added in h1.
// MODE 1: conv1 (K=32 stacked [xi|xj]). MODE 2: m1 (K=1056), fp32 out, no max.
// ---------------------------------------------------------------------------
template<int MODE>
__global__ __launch_bounds__(256, 3)
void mfma_mlp(const unsigned short* __restrict__ featbf,
              const int* __restrict__ knn,
              const unsigned short* __restrict__ W1p, const float* __restrict__ B1,
              const unsigned short* __restrict__ W2p, const float* __restrict__ B2,
              const float* __restrict__ Pp,
              float* __restrict__ outf,
              unsigned short* __restrict__ xcat, int sliceoff,
              unsigned short* __restrict__ xfl, float* __restrict__ nrm) {
    constexpr int NCHUNK  = (MODE == 2) ? 3 : 1;
    constexpr int KTPC    = (MODE == 0) ? 8 : (MODE == 1) ? 1 : 11;
    constexpr int ASTRIDE = (MODE == 0) ? 264 : (MODE == 1) ? 40 : 360;

    __shared__ unsigned short smem[64 * 360];
    __shared__ int rowi[64];
    __shared__ int rowj[64];
    __shared__ float nparts[8][4];

    const int t = threadIdx.x;
    const int l = t & 63, w = t >> 6;
    const int q4 = l >> 4, m16 = l & 15;
    const int s1 = w * 6;          // GEMM1 ntile start (21 total: 6,6,6,3)
    const int s2 = w * 4;          // GEMM2 ntile start (16 total)

    if (MODE != 2 && t < 64) {
        int pt = blockIdx.x * 8 + (t >> 3);
        rowi[t] = pt;
        rowj[t] = (pt & ~511) + knn[pt * 8 + (t & 7)];
    }

    f32x4 acc1[4][6];
    #pragma unroll
    for (int mt = 0; mt < 4; ++mt)
        #pragma unroll
        for (int n = 0; n < 6; ++n) acc1[mt][n] = (f32x4){0.f, 0.f, 0.f, 0.f};

    auto g1 = [&](auto c1c, int ktbase) {
        constexpr int C1 = decltype(c1c)::value;
        #pragma unroll 1
        for (int kt = 0; kt < KTPC; ++kt) {
            bf16x8 af[4];
            #pragma unroll
            for (int mt = 0; mt < 4; ++mt)
                af[mt] = *(const bf16x8*)&smem[(mt * 16 + m16) * ASTRIDE + q4 * 8 + kt * 32];
            const unsigned short* bp =
                W1p + ((size_t)((ktbase + kt) * 21 + s1) * 64 + l) * 8;
            #pragma unroll
            for (int n = 0; n < C1; ++n) {
                bf16x8 bf = *(const bf16x8*)(bp + n * 512);
                #pragma unroll
                for (int mt = 0; mt < 4; ++mt)
                    acc1[mt][n] = __builtin_amdgcn_mfma_f32_16x16x32_bf16(af[mt], bf, acc1[mt][n], 0, 0, 0);
            }
        }
    };

    for (int kc = 0; kc < NCHUNK; ++kc) {
        __syncthreads();
        if constexpr (MODE == 0) {
            // stage xj rows only (K=256 hi half)
            const int r = t >> 2;
            const unsigned short* srow = featbf + (size_t)rowj[r] * 512;
            #pragma unroll
            for (int s = 0; s < 8; ++s) {
                int c16 = (t & 3) + (s << 2);
                *(uint4*)&smem[r * 264 + c16 * 8] = *(const uint4*)(srow + c16 * 8);
            }
        } else if constexpr (MODE == 1) {
            const int r = t >> 2, c16 = t & 3;
            const unsigned short* s2p =
                featbf + (size_t)(c16 < 2 ? rowi[r] : rowj[r]) * 16 + (c16 & 1) * 8;
            *(uint4*)&smem[r * 40 + c16 * 8] = *(const uint4*)s2p;
        } else {
            const int r = t >> 2;
            const unsigned short* srow =
                featbf + (size_t)(blockIdx.x * 64 + r) * 1056 + kc * 352;
            #pragma unroll
            for (int s = 0; s < 11; ++s) {
                int c16 = (t & 3) + (s << 2);
                *(uint4*)&smem[r * 360 + c16 * 8] = *(const uint4*)(srow + c16 * 8);
            }
        }
        __syncthreads();

        if (w < 3) g1(IC<6>{}, kc * KTPC);
        else       g1(IC<3>{}, kc * KTPC);
    }
    __syncthreads();

    // h1 = lrelu(acc1 [+ P] + b1) -> bf16 LDS [64][360]; cols 336..351 zeroed
    {
        const int c1 = (w < 3) ? 6 : 3;
        for (int n = 0; n < c1; ++n) {
            int nt = s1 + n;
            float b = B1[nt * 16 + m16];
            #pragma unroll
            for (int mt = 0; mt < 4; ++mt)
                #pragma unroll
                for (int r = 0; r < 4; ++r) {
                    int row = mt * 16 + q4 * 4 + r;
                    float v = acc1[mt][n][r] + b;
                    if constexpr (MODE == 0)
                        v += Pp[(size_t)(blockIdx.x * 8 + (row >> 3)) * 336 + nt * 16 + m16];
                    smem[row * 360 + nt * 16 + m16] = f2bf(lrelu(v));
                }
        }
    }
    if (t < 64) {
        #pragma unroll
        for (int c = 336; c < 352; ++c) smem[t * 360 + c] = 0;
    }
    __syncthreads();

    // GEMM2: h1[64][352] x W2 slice (4 ntiles per wave)
    f32x4 acc2[4][4];
    #pragma unroll
    for (int mt = 0; mt < 4; ++mt)
        #pragma unroll
        for (int n = 0; n < 4; ++n) acc2[mt][n] = (f32x4){0.f, 0.f, 0.f, 0.f};
    #pragma unroll 1
    for (int kt = 0; kt < 11; ++kt) {
        bf16x8 af[4];
        #pragma unroll
        for (int mt = 0; mt < 4; ++mt)
            af[mt] = *(const bf16x8*)&smem[(mt * 16 + m16) * 360 + q4 * 8 + kt * 32];
        const unsigned short* bp = W2p + ((size_t)(kt * 16 + s2) * 64 + l) * 8;
        #pragma unroll
        for (int n = 0; n < 4; ++n) {
            bf16x8 bf = *(const bf16x8*)(bp + n * 512);
            #pragma unroll
            for (int mt = 0; mt < 4; ++mt)
                acc2[mt][n] = __builtin_amdgcn_mfma_f32_16x16x32_bf16(af[mt], bf, acc2[mt][n], 0, 0, 0);
        }
    }

    if constexpr (MODE != 2) {
        // max over 8 edges -> stage hi|lo into LDS, then coalesced stores
        __syncthreads();
        unsigned short* sh = smem;          // [8][512]: 0..255 hi, 256..511 lo
        #pragma unroll
        for (int mt = 0; mt < 4; ++mt) {
            float nsum = 0.f;
            int plocal = mt * 2 + (q4 >> 1);
            #pragma unroll
            for (int n = 0; n < 4; ++n) {
                int nt = s2 + n;
                float b = B2[nt * 16 + m16];
                float mv = -3.4e38f;
                #pragma unroll
                for (int r = 0; r < 4; ++r) mv = fmaxf(mv, lrelu(acc2[mt][n][r] + b));
                mv = fmaxf(mv, __shfl_xor(mv, 16, 64));
                if ((q4 & 1) == 0) {
                    int col = nt * 16 + m16;
                    unsigned short hi = f2bf(mv);
                    float fhi = bf2f(hi);
                    unsigned short lo = f2bf(mv - fhi);
                    float xr = fhi + bf2f(lo);
                    nsum += xr * xr;
                    sh[plocal * 512 + col] = hi;
                    sh[plocal * 512 + 256 + col] = lo;
                }
            }
            #pragma unroll
            for (int o = 1; o < 16; o <<= 1) nsum += __shfl_xor(nsum, o, 64);
            if ((q4 & 1) == 0 && m16 == 0) nparts[plocal][w] = nsum;
        }
        __syncthreads();
        {
            int r = t >> 5, cb = (t & 31) * 16;
            int p = blockIdx.x * 8 + r;
            uint4 v0 = *(uint4*)&sh[r * 512 + cb];
            uint4 v1 = *(uint4*)&sh[r * 512 + cb + 8];
            *(uint4*)&xfl[(size_t)p * 512 + cb]     = v0;
            *(uint4*)&xfl[(size_t)p * 512 + cb + 8] = v1;
            if (cb < 256) {
                *(uint4*)&xcat[(size_t)p * 1056 + sliceoff + cb]     = v0;
                *(uint4*)&xcat[(size_t)p * 1056 + sliceoff + cb + 8] = v1;
            }
        }
        if (t < 8)
            nrm[blockIdx.x * 8 + t] =
                nparts[t][0] + nparts[t][1] + nparts[t][2] + nparts[t][3];
    } else {
        #pragma unroll
        for (int mt = 0; mt < 4; ++mt)
            #pragma unroll
            for (int n = 0; n < 4; ++n) {
                int nt = s2 + n;
                float b = B2[nt * 16 + m16];
                int col = nt * 16 + m16;
                #pragma unroll
                for (int r = 0; r < 4; ++r) {
                    int p = blockIdx.x * 64 + mt * 16 + q4 * 4 + r;
                    outf[(size_t)p * 256 + col] = lrelu(acc2[mt][n][r] + b);
                }
            }
    }
}

// ---------------------------------------------------------------------------
__global__ __launch_bounds__(256) void pool_kernel(const float* __restrict__ h,
                                                   float* __restrict__ g) {
    int b = blockIdx.x, t = threadIdx.x;
    const float* hb = h + (size_t)b * 512 * 256;
    float s = 0.f;
    for (int n = 0; n < 512; ++n) s += hb[n * 256 + t];
    g[b * 256 + t] = s * (1.f / 512.f);
}

__global__ __launch_bounds__(128) void head_kernel(const float* __restrict__ g,
                                                   const float* __restrict__ w1,
                                                   const float* __restrict__ b1,
                                                   const float* __restrict__ w2,
                                                   const float* __restrict__ b2,
                                                   float* __restrict__ out) {
    __shared__ float gs[256];
    __shared__ float hid[128];
    int b = blockIdx.x, t = threadIdx.x;
    gs[t] = g[b * 256 + t];
    gs[t + 128] = g[b * 256 + t + 128];
    __syncthreads();
    float s = b1[t];
    for (int c = 0; c < 256; ++c) s += gs[c] * w1[c * 128 + t];
    hid[t] = lrelu(s);
    __syncthreads();
    if (t < 3) {
        float o = b2[t];
        for (int j = 0; j < 128; ++j) o += hid[j] * w2[j * 3 + t];
        out[b * 3 + t] = o;
    }
}

// ---------------------------------------------------------------------------
extern "C" void kernel_launch(void* const* d_in, const int* in_sizes, int n_in,
                              void* d_out, int out_size, void* d_ws, size_t ws_size,
                              hipStream_t stream) {
    const float* xb = (const float*)d_in[0];
    const float* c_w1[4] = { (const float*)d_in[3],  (const float*)d_in[7],
                             (const float*)d_in[11], (const float*)d_in[15] };
    const float* c_b1[4] = { (const float*)d_in[4],  (const float*)d_in[8],
                             (const float*)d_in[12], (const float*)d_in[16] };
    const float* c_w2[4] = { (const float*)d_in[5],  (const float*)d_in[9],
                             (const float*)d_in[13], (const float*)d_in[17] };
    const float* c_b2[4] = { (const float*)d_in[6],  (const float*)d_in[10],
                             (const float*)d_in[14], (const float*)d_in[18] };
    const float* m1w1 = (const float*)d_in[19];
    const float* m1b1 = (const float*)d_in[20];
    const float* m1w2 = (const float*)d_in[21];
    const float* m1b2 = (const float*)d_in[22];
    const float* m2w1 = (const float*)d_in[23];
    const float* m2b1 = (const float*)d_in[24];
    const float* m2w2 = (const float*)d_in[25];
    const float* m2b2 = (const float*)d_in[26];

    char* base = (char*)d_ws;
    size_t off = 0;
    auto alloc = [&](size_t bytes) { char* p = base + off; off = (off + bytes + 255) & ~(size_t)255; return p; };
    int*            knn   = (int*)           alloc((size_t)32768 * 8 * 4);
    float*          nrm   = (float*)         alloc((size_t)32768 * 4);
    float*          Pp    = (float*)         alloc((size_t)32768 * 336 * 4); // aliased: hm after last conv
    float*          g     = (float*)         alloc(64 * 256 * 4);
    unsigned short* xcat  = (unsigned short*)alloc((size_t)32768 * 1056 * 2);
    unsigned short* xfl   = (unsigned short*)alloc((size_t)32768 * 512 * 2);
    unsigned short* xbbf  = (unsigned short*)alloc((size_t)32768 * 16 * 2);
    unsigned short* w1p1  = (unsigned short*)alloc((size_t)1  * 21 * 512 * 2);
    unsigned short* w2p1  = (unsigned short*)alloc((size_t)11 * 16 * 512 * 2);
    unsigned short* w1a[3]; unsigned short* w1b[3]; unsigned short* w2p[3];
    for (int i = 0; i < 3; ++i) {
        w1a[i] = (unsigned short*)alloc((size_t)8  * 21 * 512 * 2);
        w1b[i] = (unsigned short*)alloc((size_t)8  * 21 * 512 * 2);
        w2p[i] = (unsigned short*)alloc((size_t)11 * 16 * 512 * 2);
    }
    unsigned short* m1p1  = (unsigned short*)alloc((size_t)33 * 21 * 512 * 2);
    unsigned short* m1p2  = (unsigned short*)alloc((size_t)11 * 16 * 512 * 2);
    float* hm = Pp;   // m1 output reuses the P buffer (P dead by then)

    PTable tb;
    tb.d[0] = { c_w1[0], w1p1, 1,  21, 336, 1, 16,  6,   0   };
    tb.d[1] = { c_w2[0], w2p1, 11, 16, 256, 0, 0,   0,   336 };
    for (int i = 0; i < 3; ++i) {
        tb.d[2 + 3 * i] = { c_w1[i + 1], w1a[i], 8,  21, 336, 1, 0,   256, 0   };
        tb.d[3 + 3 * i] = { c_w1[i + 1], w1b[i], 8,  21, 336, 3, 256, 0,   0   };
        tb.d[4 + 3 * i] = { c_w2[i + 1], w2p[i], 11, 16, 256, 0, 0,   0,   336 };
    }
    tb.d[11] = { m1w1, m1p1, 33, 21, 336, 2, 0, 0, 0   };
    tb.d[12] = { m1w2, m1p2, 11, 16, 256, 0, 0, 0, 336 };
    pack_kernel<<<dim3(1386, 13), dim3(256), 0, stream>>>(tb);
    xbprep_kernel<<<128, 256, 0, stream>>>(xb, xbbf, xcat);

    // layer 1 (F=6): fp32 kNN on xb, conv1 writes xfl/xcat-slice/norm of x1
    norms_kernel<6><<<128, 256, 0, stream>>>(xb, nrm);
    knn_kernel<6><<<1024, 256, 0, stream>>>(xb, nrm, knn);
    mfma_mlp<1><<<4096, 256, 0, stream>>>(xbbf, knn,
                                          w1p1, c_b1[0], w2p1, c_b2[0], nullptr,
                                          nullptr, xcat, 32, xfl, nrm);

    // layers 2..4: MFMA kNN + point-GEMM + conv
    for (int l = 1; l < 4; ++l) {
        int dstslice = 32 + l * 256;
        knn_mfma<<<512, 256, 0, stream>>>(xfl, nrm, knn);
        pgemm_kernel<<<512, 256, 0, stream>>>(xfl, w1a[l - 1], Pp);
        mfma_mlp<0><<<4096, 256, 0, stream>>>(xfl, knn,
                                              w1b[l - 1], c_b1[l], w2p[l - 1], c_b2[l], Pp,
                                              nullptr, xcat, dstslice, xfl, nrm);
    }

    // m1 over Xcat (hm aliases Pp — P is dead now)
    mfma_mlp<2><<<512, 256, 0, stream>>>(xcat, nullptr,
                                         m1p1, m1b1, m1p2, m1b2, nullptr,
                                         hm, nullptr, 0, nullptr, nullptr);

    pool_kernel<<<64, 256, 0, stream>>>(hm, g);
    head_kernel<<<64, 128, 0, stream>>>(g, m2w1, m2b1, m2w2, m2b2, (float*)d_out);
}